// Round 13
// baseline (739.433 us; speedup 1.0000x reference)
//
#include <hip/hip_runtime.h>
#include <hip/hip_bf16.h>
#include <math.h>

#define H 8
#define DK 32
#define NHID 256
#define LNUM 2
#define GNUM 16

typedef float f32x4 __attribute__((ext_vector_type(4)));
typedef short bf16x8 __attribute__((ext_vector_type(8)));
typedef unsigned short u16x8 __attribute__((ext_vector_type(8)));

__device__ __forceinline__ unsigned encf(float f) {
    unsigned u = __float_as_uint(f);
    return (u & 0x80000000u) ? ~u : (u | 0x80000000u);
}
__device__ __forceinline__ float decf(unsigned u) {
    return __uint_as_float((u & 0x80000000u) ? (u ^ 0x80000000u) : ~u);
}
__device__ __forceinline__ float bfd(unsigned short u) {
    return __uint_as_float(((unsigned)u) << 16);
}
__device__ __forceinline__ unsigned short f2bf(float x) {
    __hip_bfloat16 b = __float2bfloat16(x);
    return *reinterpret_cast<unsigned short*>(&b);
}

// Panel swizzle: 64-row panels, LDS-image layout. kb = byte offset in 512B row.
#define APAN2(row, kb) ((((kb) >> 7) << 12) + ((row) << 6) + ((((kb) & 127) ^ (((row) & 7) << 4)) >> 1))
__device__ __forceinline__ size_t swzA(int row, int col /*elem*/) {
    return (((size_t)(row >> 6)) << 14) + (size_t)APAN2(row & 63, col * 2);
}
#define SWZB(row, kb)  (((row) << 6) + ((((kb) ^ (((row) & 7) << 4))) >> 1))

// ---------- by-value arg structs ----------
struct CsrArgs { const int* dst[8]; int relOfs[9]; int dstBase[8]; };
struct BdArgs  { const unsigned short* inK[3]; const unsigned short* inV[3];
                 const float* RA[3]; const float* RM[3]; const float* priP[3];
                 int rows[3]; int rowOfs[3]; };
struct Ek1Args { const int* src[3]; const int* dst[3]; int E[3]; int eBase[3]; int rowOfs[3]; };
struct Ek3Args { const int* src[3]; const int* tim[3]; int eBase[3]; int dstBase[3];
                 int rowOfs[3]; int nr; int nD; };
struct GmaxArgs{ const float* hp[3]; const int* grp[3]; int n[3]; int colBase[3]; };
struct GBArgs  { int rb[4]; int nLoc[3]; int li3; };
struct MLArgs  { int rowOfs[4]; int nLoc[3]; int li3; };

// ---------- temporal encoding table ----------
__global__ void te_kernel(const float* __restrict__ time_tab, const float* __restrict__ time_w,
                          const float* __restrict__ time_b, float* __restrict__ te7) {
    int t = threadIdx.x >> 5, j = threadIdx.x & 31;
    if (t < 7) {
        float s = time_b[j];
        #pragma unroll
        for (int i = 0; i < 32; ++i) s += time_tab[t * 32 + i] * time_w[i * 32 + j];
        te7[t * 32 + j] = s;
    }
}

__global__ void gather_rows(const float* __restrict__ emb, const int* __restrict__ idx,
                            float* __restrict__ out, unsigned short* __restrict__ outB, int n) {
    int row = blockIdx.x, c = threadIdx.x;
    if (row < n) {
        float v = emb[(size_t)idx[row] * 256 + c];
        out[(size_t)row * 256 + c] = v;
        outB[swzA(row, c)] = f2bf(v);
    }
}

__global__ void bcast_row(const float* __restrict__ src, float* __restrict__ out,
                          unsigned short* __restrict__ outB, int n) {
    int row = blockIdx.x, c = threadIdx.x;
    if (row < n) {
        float v = src[c];
        out[(size_t)row * 256 + c] = v;
        outB[swzA(row, c)] = f2bf(v);
    }
}

// ---------- weight transpose+bf16: tile-linear pre-swizzled chunks ----------
// WT[z] elem (col,k) -> ((col>>6)*4 + (k>>6))*4096 + SWZB(col&63, (k&63)*2)
__global__ __launch_bounds__(256) void wtr_kernel(
    const float* __restrict__ adaptW, const float* __restrict__ kW, const float* __restrict__ qW,
    const float* __restrict__ vW, const float* __restrict__ aW, unsigned short* __restrict__ WT) {
    int z = blockIdx.z;
    const float* src;
    if (z == 0) src = adaptW;
    else if (z < 7)  src = kW + (size_t)(z - 1) * 65536;
    else if (z < 13) src = qW + (size_t)(z - 7) * 65536;
    else if (z < 19) src = vW + (size_t)(z - 13) * 65536;
    else             src = aW + (size_t)(z - 19) * 65536;
    unsigned short* dst = WT + (size_t)z * 65536;
    __shared__ float tile[32][33];
    int tx = threadIdx.x & 31, ty = threadIdx.x >> 5;
    int kb = blockIdx.x * 32, cb = blockIdx.y * 32;
    #pragma unroll
    for (int i = 0; i < 4; ++i)
        tile[ty + i * 8][tx] = src[(size_t)(kb + ty + i * 8) * 256 + cb + tx];
    __syncthreads();
    #pragma unroll
    for (int i = 0; i < 4; ++i) {
        int col = cb + ty + i * 8, k = kb + tx;
        dst[((col >> 6) * 4 + (k >> 6)) * 4096 + SWZB(col & 63, (k & 63) * 2)] =
            f2bf(tile[tx][ty + i * 8]);
    }
}

// ---------- batched MFMA GEMM over concat rows, 128-col blocks, chunk-linear B ----------
// grid (totRowBlocks, 2). Wave wv: rows (wv&1)*32, col-chunk wv>>1 (64 cols). acc 2x4.
__global__ __launch_bounds__(256) void gemm_batch(
    const unsigned short* __restrict__ Apan,
    const unsigned short* __restrict__ WT, int wBase, int nz,
    const float* __restrict__ b0, const float* __restrict__ b1, const float* __restrict__ b2,
    void* __restrict__ o0, void* __restrict__ o1, void* __restrict__ o2,
    int outBf16, GBArgs ga)
{
    __shared__ unsigned short As[64 * 256];     // 32 KB
    __shared__ unsigned short Bs[2][8192];      // 2 x 16 KB (2 chunks of 64x64)
    const int tid = threadIdx.x;
    const int lane = tid & 63, wv = tid >> 6;
    const int b = blockIdx.x;
    const int t = (b >= ga.rb[2]) ? 2 : ((b >= ga.rb[1]) ? 1 : 0);
    const int nLoc = ga.nLoc[t];
    const int locRowBase = (b - ga.rb[t]) * 64;
    const int cb2 = blockIdx.y;                 // 0/1 -> cols [cb2*128, +128)
    const int mBase = wBase + ga.li3 + t;
    // ---- stage A panel (linear copy) ----
    {
        const u16x8* src = reinterpret_cast<const u16x8*>(Apan + (((size_t)b) << 14));
        u16x8* dst = reinterpret_cast<u16x8*>(As);
        #pragma unroll
        for (int it = 0; it < 8; ++it)
            dst[it * 256 + tid] = src[it * 256 + tid];
    }
    const int fr = lane & 15, fg = lane >> 4;
    const int wrow = (wv & 1) * 32, cc = wv >> 1;
    const int nt = nz * 4;
    // prologue: stage step-0 chunks
    {
        const unsigned short* base0 = WT + (size_t)mBase * 65536;
        u16x8* dst = reinterpret_cast<u16x8*>(Bs[0]);
        #pragma unroll
        for (int j2 = 0; j2 < 4; ++j2) {
            int e = tid + j2 * 256;
            int ch = e >> 9, eo = e & 511;
            dst[e] = *reinterpret_cast<const u16x8*>(base0 + ((cb2 * 2 + ch) * 4 + 0) * 4096 + eo * 8);
        }
    }
    __syncthreads();

    f32x4 acc[2][4];
    #pragma unroll
    for (int m = 0; m < 2; ++m)
        #pragma unroll
        for (int nn = 0; nn < 4; ++nn) acc[m][nn] = 0.f;

    for (int tt2 = 0; tt2 < nt; ++tt2) {
        const int cur = tt2 & 1;
        const int ks = tt2 & 3, z = tt2 >> 2;
        u16x8 w[4];
        const bool pf = (tt2 + 1 < nt);
        if (pf) {
            int tn = tt2 + 1;
            const unsigned short* baseN = WT + (size_t)(mBase + (tn >> 2) * 6) * 65536;
            int ksN = tn & 3;
            #pragma unroll
            for (int j2 = 0; j2 < 4; ++j2) {
                int e = tid + j2 * 256;
                int ch = e >> 9, eo = e & 511;
                w[j2] = *reinterpret_cast<const u16x8*>(baseN + ((cb2 * 2 + ch) * 4 + ksN) * 4096 + eo * 8);
            }
        }
        #pragma unroll
        for (int kk = 0; kk < 2; ++kk) {
            bf16x8 af0 = *reinterpret_cast<bf16x8*>(&As[APAN2(wrow + fr,      ks * 128 + kk * 64 + fg * 16)]);
            bf16x8 af1 = *reinterpret_cast<bf16x8*>(&As[APAN2(wrow + 16 + fr, ks * 128 + kk * 64 + fg * 16)]);
            bf16x8 bf[4];
            #pragma unroll
            for (int nn = 0; nn < 4; ++nn)
                bf[nn] = *reinterpret_cast<bf16x8*>(&Bs[cur][cc * 4096 + SWZB(nn * 16 + fr, kk * 64 + fg * 16)]);
            #pragma unroll
            for (int nn = 0; nn < 4; ++nn) {
                acc[0][nn] = __builtin_amdgcn_mfma_f32_16x16x32_bf16(af0, bf[nn], acc[0][nn], 0, 0, 0);
                acc[1][nn] = __builtin_amdgcn_mfma_f32_16x16x32_bf16(af1, bf[nn], acc[1][nn], 0, 0, 0);
            }
        }
        if (pf) {
            u16x8* dst = reinterpret_cast<u16x8*>(Bs[cur ^ 1]);
            #pragma unroll
            for (int j2 = 0; j2 < 4; ++j2)
                dst[tid + j2 * 256] = w[j2];
        }
        if (ks == 3) {
            const float* biasB = (z == 0) ? b0 : ((z == 1) ? b1 : b2);
            const float* bias = biasB + (size_t)(ga.li3 + t) * 256;
            void* outp = (z == 0) ? o0 : ((z == 1) ? o1 : o2);
            #pragma unroll
            for (int m = 0; m < 2; ++m) {
                #pragma unroll
                for (int r = 0; r < 4; ++r) {
                    int lr = locRowBase + wrow + m * 16 + fg * 4 + r;
                    if (lr >= nLoc) continue;
                    size_t gr = (size_t)b * 64 + wrow + m * 16 + fg * 4 + r;
                    #pragma unroll
                    for (int nn = 0; nn < 4; ++nn) {
                        int gc = cb2 * 128 + cc * 64 + nn * 16 + fr;
                        float v = acc[m][nn][r] + bias[gc];
                        if (outBf16) ((unsigned short*)outp)[gr * 256 + gc] = f2bf(v);
                        else         ((float*)outp)[gr * 256 + gc] = v;
                    }
                }
            }
            #pragma unroll
            for (int m = 0; m < 2; ++m)
                #pragma unroll
                for (int nn = 0; nn < 4; ++nn) acc[m][nn] = 0.f;
        }
        __syncthreads();
    }
}

// ---------- init GEMM (word adapt): f32 gather A, chunk-linear B, 64-col blocks ----------
__global__ __launch_bounds__(256) void gemm_init(
    const float* __restrict__ A, const int* __restrict__ gidx,
    const unsigned short* __restrict__ WT, const float* __restrict__ bias,
    float* __restrict__ outF, unsigned short* __restrict__ dupB, int n)
{
    __shared__ unsigned short As[64 * 256];
    __shared__ unsigned short Bs[2][4096];
    const int tid = threadIdx.x;
    const int lane = tid & 63, wv = tid >> 6;
    const int rowBase = blockIdx.x * 64;
    const int cb6 = blockIdx.y;   // 64-col tile
    #pragma unroll 4
    for (int it = 0; it < 16; ++it) {
        int row = it * 4 + wv;
        int r = rowBase + row;
        ushort4 p = make_ushort4(0, 0, 0, 0);
        if (r < n) {
            int ar = gidx[r];
            float4 v = *reinterpret_cast<const float4*>(A + (size_t)ar * 256 + lane * 4);
            p.x = f2bf(v.x); p.y = f2bf(v.y); p.z = f2bf(v.z); p.w = f2bf(v.w);
        }
        *reinterpret_cast<ushort4*>(&As[APAN2(row, lane * 8)]) = p;
    }
    const int fr = lane & 15, fg = lane >> 4;
    const int wrow = (wv & 1) * 32, wcol = (wv >> 1) * 32;
    {
        u16x8* dst = reinterpret_cast<u16x8*>(Bs[0]);
        #pragma unroll
        for (int j2 = 0; j2 < 2; ++j2) {
            int e = tid + j2 * 256;
            dst[e] = *reinterpret_cast<const u16x8*>(WT + (cb6 * 4 + 0) * 4096 + e * 8);
        }
    }
    __syncthreads();
    f32x4 acc[2][2];
    #pragma unroll
    for (int m = 0; m < 2; ++m)
        #pragma unroll
        for (int nn = 0; nn < 2; ++nn) acc[m][nn] = 0.f;
    for (int t = 0; t < 4; ++t) {
        const int cur = t & 1;
        u16x8 w[2];
        const bool pf = (t + 1 < 4);
        if (pf) {
            #pragma unroll
            for (int j2 = 0; j2 < 2; ++j2) {
                int e = tid + j2 * 256;
                w[j2] = *reinterpret_cast<const u16x8*>(WT + (cb6 * 4 + t + 1) * 4096 + e * 8);
            }
        }
        #pragma unroll
        for (int kk = 0; kk < 2; ++kk) {
            bf16x8 af0 = *reinterpret_cast<bf16x8*>(&As[APAN2(wrow + fr,      t * 128 + kk * 64 + fg * 16)]);
            bf16x8 af1 = *reinterpret_cast<bf16x8*>(&As[APAN2(wrow + 16 + fr, t * 128 + kk * 64 + fg * 16)]);
            bf16x8 bf0 = *reinterpret_cast<bf16x8*>(&Bs[cur][SWZB(wcol + fr,      kk * 64 + fg * 16)]);
            bf16x8 bf1 = *reinterpret_cast<bf16x8*>(&Bs[cur][SWZB(wcol + 16 + fr, kk * 64 + fg * 16)]);
            acc[0][0] = __builtin_amdgcn_mfma_f32_16x16x32_bf16(af0, bf0, acc[0][0], 0, 0, 0);
            acc[0][1] = __builtin_amdgcn_mfma_f32_16x16x32_bf16(af0, bf1, acc[0][1], 0, 0, 0);
            acc[1][0] = __builtin_amdgcn_mfma_f32_16x16x32_bf16(af1, bf0, acc[1][0], 0, 0, 0);
            acc[1][1] = __builtin_amdgcn_mfma_f32_16x16x32_bf16(af1, bf1, acc[1][1], 0, 0, 0);
        }
        if (pf) {
            u16x8* dst = reinterpret_cast<u16x8*>(Bs[cur ^ 1]);
            #pragma unroll
            for (int j2 = 0; j2 < 2; ++j2)
                dst[tid + j2 * 256] = w[j2];
        }
        __syncthreads();
    }
    #pragma unroll
    for (int m = 0; m < 2; ++m) {
        #pragma unroll
        for (int r = 0; r < 4; ++r) {
            int gr = rowBase + wrow + m * 16 + fg * 4 + r;
            if (gr >= n) continue;
            #pragma unroll
            for (int nn = 0; nn < 2; ++nn) {
                int gc = cb6 * 64 + wcol + nn * 16 + fr;
                float v = acc[m][nn][r] + bias[gc];
                outF[(size_t)gr * 256 + gc] = v;
                dupB[swzA(gr, gc)] = f2bf(v);
            }
        }
    }
}

// ---------- MFMA block-diagonal transform ----------
__global__ __launch_bounds__(256) void bd_mfma(
    unsigned short* __restrict__ katt, unsigned short* __restrict__ vmsg, BdArgs A)
{
    const int rr = blockIdx.z >> 1, isV = blockIdx.z & 1;
    const int n = A.rows[rr];
    const int rowBase = blockIdx.x * 128;
    if (rowBase >= n) return;
    const unsigned short* in = isV ? A.inV[rr] : A.inK[rr];
    const float* R = isV ? A.RM[rr] : A.RA[rr];
    unsigned short* out = (isV ? vmsg : katt) + (size_t)A.rowOfs[rr] * 256;
    const int head = blockIdx.y;
    const float oscale = isV ? 1.f : (A.priP[rr][head] * 0.17677669529663687f);
    const int tid = threadIdx.x, lane = tid & 63, wv = tid >> 6;
    const int fr = lane & 15, fg = lane >> 4;
    const float* Rh = R + head * 1024;
    bf16x8 b0, b1;
    #pragma unroll
    for (int j = 0; j < 8; ++j) {
        b0[j] = (short)f2bf(Rh[(fg * 8 + j) * 32 + fr] * oscale);
        b1[j] = (short)f2bf(Rh[(fg * 8 + j) * 32 + 16 + fr] * oscale);
    }
    const int r0 = rowBase + wv * 32 + fr;
    const int r1 = r0 + 16;
    const int rc0 = (r0 < n) ? r0 : n - 1;
    const int rc1 = (r1 < n) ? r1 : n - 1;
    bf16x8 a0 = *reinterpret_cast<const bf16x8*>(in + (size_t)rc0 * 256 + head * 32 + fg * 8);
    bf16x8 a1 = *reinterpret_cast<const bf16x8*>(in + (size_t)rc1 * 256 + head * 32 + fg * 8);
    f32x4 acc00 = 0.f, acc01 = 0.f, acc10 = 0.f, acc11 = 0.f;
    acc00 = __builtin_amdgcn_mfma_f32_16x16x32_bf16(a0, b0, acc00, 0, 0, 0);
    acc01 = __builtin_amdgcn_mfma_f32_16x16x32_bf16(a0, b1, acc01, 0, 0, 0);
    acc10 = __builtin_amdgcn_mfma_f32_16x16x32_bf16(a1, b0, acc10, 0, 0, 0);
    acc11 = __builtin_amdgcn_mfma_f32_16x16x32_bf16(a1, b1, acc11, 0, 0, 0);
    const int colB = head * 32 + fr;
    #pragma unroll
    for (int r = 0; r < 4; ++r) {
        int g0 = rowBase + wv * 32 + fg * 4 + r;
        if (g0 < n) {
            out[(size_t)g0 * 256 + colB]      = f2bf(acc00[r]);
            out[(size_t)g0 * 256 + colB + 16] = f2bf(acc01[r]);
        }
        int g1 = g0 + 16;
        if (g1 < n) {
            out[(size_t)g1 * 256 + colB]      = f2bf(acc10[r]);
            out[(size_t)g1 * 256 + colB + 16] = f2bf(acc11[r]);
        }
    }
}

// ---------- EK1 for a group ----------
__global__ __launch_bounds__(256) void ek1_group(
    const unsigned short* __restrict__ qbuf, const unsigned short* __restrict__ katt,
    float* __restrict__ alog, Ek1Args A)
{
    const int rr = blockIdx.y;
    int gid = blockIdx.x * 256 + threadIdx.x;
    int e = gid >> 3, h = gid & 7;
    if (e >= A.E[rr]) return;
    int s = A.src[rr][e], d = A.dst[rr][e];
    const u16x8* q8 = reinterpret_cast<const u16x8*>(qbuf + (size_t)d * 256 + h * 32);
    const u16x8* k8 = reinterpret_cast<const u16x8*>(katt + ((size_t)(A.rowOfs[rr] + s)) * 256 + h * 32);
    float a = 0.f;
    #pragma unroll
    for (int j = 0; j < 4; ++j) {
        u16x8 qv = q8[j], kv = k8[j];
        #pragma unroll
        for (int m = 0; m < 8; ++m) a += bfd(qv[m]) * bfd(kv[m]);
    }
    alog[(size_t)(A.eBase[rr] + e) * 8 + h] = a;
}

// ---------- EK3: wave per dst, single-pass online softmax, swizzled bf16 out ----------
__global__ __launch_bounds__(256) void ek3_group(
    const unsigned short* __restrict__ vmsg, const float* __restrict__ alog,
    const int* __restrict__ rowptrAll, const int* __restrict__ eidxAll,
    const float* __restrict__ te7, unsigned short* __restrict__ tacc, float outScale, Ek3Args A)
{
    __shared__ float sTe[224];
    if (threadIdx.x < 224) sTe[threadIdx.x] = te7[threadIdx.x];
    __syncthreads();
    int wv = threadIdx.x >> 6, lane = threadIdx.x & 63;
    int d = blockIdx.x * 4 + wv;
    if (d >= A.nD) return;
    const int bl = lane >> 3, hl = lane & 7;
    const int c = lane * 4, hq = lane >> 3;
    float t0 = 0.f, t1 = 0.f, t2 = 0.f, t3 = 0.f;
    for (int rr = 0; rr < A.nr; ++rr) {
        int base = A.dstBase[rr] + d;
        int beg = rowptrAll[base], end = rowptrAll[base + 1];
        if (beg == end) continue;
        const int* srcp = A.src[rr];
        const int* timp = A.tim[rr];
        int eB = A.eBase[rr], rO = A.rowOfs[rr];
        float m = -INFINITY, den = 0.f;
        float a0 = 0.f, a1 = 0.f, a2 = 0.f, a3 = 0.f;
        for (int p0 = beg; p0 < end; p0 += 8) {
            int p = p0 + bl;
            bool valid = p < end;
            int ge = eidxAll[valid ? p : end - 1];
            int le = ge - eB;
            float a = valid ? alog[(size_t)ge * 8 + hl] : -INFINITY;
            int sS = valid ? srcp[le] : 0;
            int tT = (timp && valid) ? timp[le] : 0;
            float bm = a;
            bm = fmaxf(bm, __shfl_xor(bm, 8));
            bm = fmaxf(bm, __shfl_xor(bm, 16));
            bm = fmaxf(bm, __shfl_xor(bm, 32));
            float bmA = __shfl(bm, hq);
            float mN = fmaxf(m, bmA);
            float sc = __expf(m - mN);
            den *= sc; a0 *= sc; a1 *= sc; a2 *= sc; a3 *= sc;
            m = mN;
            float mL = __shfl(mN, hl * 8);
            float ex = valid ? __expf(a - mL) : 0.f;
            float ds = ex;
            ds += __shfl_xor(ds, 8);
            ds += __shfl_xor(ds, 16);
            ds += __shfl_xor(ds, 32);
            den += __shfl(ds, hq);
            int nb = end - p0; if (nb > 8) nb = 8;
            for (int b = 0; b < nb; ++b) {
                float w = __shfl(ex, b * 8 + hq);
                int sB = __shfl(sS, b * 8);
                ushort4 v = *reinterpret_cast<const ushort4*>(vmsg + ((size_t)(rO + sB)) * 256 + c);
                float vx = bfd(v.x), vy = bfd(v.y), vz = bfd(v.z), vw = bfd(v.w);
                if (timp) {
                    int tB = __shfl(tT, b * 8);
                    const float* tp = &sTe[tB * 32 + (c & 31)];
                    vx += tp[0]; vy += tp[1]; vz += tp[2]; vw += tp[3];
                }
                a0 += w * vx; a1 += w * vy; a2 += w * vz; a3 += w * vw;
            }
        }
        float inv = 1.f / fmaxf(den, 1e-9f);
        t0 += fmaxf(a0 * inv, 0.f); t1 += fmaxf(a1 * inv, 0.f);
        t2 += fmaxf(a2 * inv, 0.f); t3 += fmaxf(a3 * inv, 0.f);
    }
    ushort4 o;
    o.x = f2bf(t0 * outScale); o.y = f2bf(t1 * outScale);
    o.z = f2bf(t2 * outScale); o.w = f2bf(t3 * outScale);
    *reinterpret_cast<ushort4*>(tacc + swzA(d, c)) = o;
}

// ---------- fused CSR build ----------
__global__ void count_all(CsrArgs A, int* __restrict__ cnt, int totE) {
    int gid = blockIdx.x * 256 + threadIdx.x;
    if (gid >= totE) return;
    int r = 0;
    while (gid >= A.relOfs[r + 1]) ++r;
    int e = gid - A.relOfs[r];
    atomicAdd(&cnt[A.dstBase[r] + A.dst[r][e]], 1);
}
__global__ __launch_bounds__(1024) void scan1_k(const int* __restrict__ cnt, int* __restrict__ part,
                                                int* __restrict__ bsum, int n) {
    __shared__ int buf[1024];
    int tid = threadIdx.x, gid = blockIdx.x * 1024 + tid;
    int x = (gid < n) ? cnt[gid] : 0;
    buf[tid] = x; __syncthreads();
    for (int off = 1; off < 1024; off <<= 1) {
        int y = (tid >= off) ? buf[tid - off] : 0;
        __syncthreads();
        buf[tid] += y;
        __syncthreads();
    }
    if (gid < n) part[gid] = buf[tid];
    if (tid == 1023) bsum[blockIdx.x] = buf[1023];
}
__global__ __launch_bounds__(256) void scan2_k(int* __restrict__ bsum, int nb) {
    __shared__ int buf[256];
    int tid = threadIdx.x;
    buf[tid] = (tid < nb) ? bsum[tid] : 0;
    __syncthreads();
    for (int off = 1; off < 256; off <<= 1) {
        int y = (tid >= off) ? buf[tid - off] : 0;
        __syncthreads();
        buf[tid] += y;
        __syncthreads();
    }
    if (tid < nb) bsum[tid] = buf[tid];
}
__global__ void scan3_k(const int* __restrict__ cnt, const int* __restrict__ part,
                        const int* __restrict__ bsum, int* __restrict__ rowptr,
                        int* __restrict__ cur, int n) {
    int gid = blockIdx.x * 256 + threadIdx.x;
    if (gid < n) {
        int b = gid >> 10;
        int add = (b > 0) ? bsum[b - 1] : 0;
        int inc = part[gid] + add;
        rowptr[gid + 1] = inc;
        cur[gid] = inc - cnt[gid];
    }
    if (gid == 0) rowptr[0] = 0;
}
__global__ void scatter_all(CsrArgs A, int* __restrict__ cur, int* __restrict__ eidx, int totE) {
    int gid = blockIdx.x * 256 + threadIdx.x;
    if (gid >= totE) return;
    int r = 0;
    while (gid >= A.relOfs[r + 1]) ++r;
    int e = gid - A.relOfs[r];
    int p = atomicAdd(&cur[A.dstBase[r] + A.dst[r][e]], 1);
    eidx[p] = gid;
}

// ---------- merged skip-mix + layernorm over concat rows ----------
__global__ __launch_bounds__(256) void mix_ln_all(
    float* __restrict__ h, unsigned short* __restrict__ hB, const float* __restrict__ trans,
    const float* __restrict__ skipP, const float* __restrict__ g, const float* __restrict__ b,
    MLArgs M)
{
    int row = blockIdx.x;
    int t = (row >= M.rowOfs[2]) ? 2 : ((row >= M.rowOfs[1]) ? 1 : 0);
    int d = row - M.rowOfs[t];
    if (d >= M.nLoc[t]) return;
    int j = M.li3 + t;
    int c = threadIdx.x;
    float alpha = 1.f / (1.f + expf(-skipP[j]));
    size_t off = (size_t)row * 256 + c;
    float o = trans[off] * alpha + h[off] * (1.f - alpha);
    float s = o, ss = o * o;
    #pragma unroll
    for (int dd = 1; dd < 64; dd <<= 1) { s += __shfl_xor(s, dd); ss += __shfl_xor(ss, dd); }
    __shared__ float rS[4], rSS[4];
    int w = threadIdx.x >> 6, lane = threadIdx.x & 63;
    if (lane == 0) { rS[w] = s; rSS[w] = ss; }
    __syncthreads();
    float S = rS[0] + rS[1] + rS[2] + rS[3];
    float SS = rSS[0] + rSS[1] + rSS[2] + rSS[3];
    float mean = S * (1.f / 256.f);
    float var = fmaxf(SS * (1.f / 256.f) - mean * mean, 0.f);
    float rs = rsqrtf(var + 1e-5f);
    float v = (o - mean) * rs * g[(size_t)j * 256 + c] + b[(size_t)j * 256 + c];
    h[off] = v;
    hB[swzA(row, c)] = f2bf(v);
}

// ---------- group max ----------
__global__ __launch_bounds__(256) void gmax_all(GmaxArgs A, unsigned* __restrict__ gi) {
    int ty = blockIdx.y;
    int n = A.n[ty];
    int r0 = blockIdx.x * 64;
    if (r0 >= n) return;
    int col = threadIdx.x;
    const float* hp = A.hp[ty];
    const int* grp = A.grp[ty];
    int cbase = A.colBase[ty];
    int rend = (r0 + 64 < n) ? r0 + 64 : n;
    int cur = grp[r0];
    float m = -INFINITY;
    for (int r = r0; r < rend; ++r) {
        int g = grp[r];
        if (g != cur) {
            atomicMax(&gi[cur * 768 + cbase + col], encf(m));
            cur = g; m = -INFINITY;
        }
        m = fmaxf(m, hp[(size_t)r * 256 + col]);
    }
    atomicMax(&gi[cur * 768 + cbase + col], encf(m));
}

__global__ void gi_init(unsigned* __restrict__ gi) {
    int i = blockIdx.x * 256 + threadIdx.x;
    if (i < 16 * 768) gi[i] = 0x007FFFFFu;
}

// ---------- final ----------
__global__ __launch_bounds__(1024) void final_k(const unsigned* __restrict__ gi,
                                                const float* __restrict__ out_w,
                                                const float* __restrict__ out_b,
                                                const float* __restrict__ y,
                                                float* __restrict__ out) {
    int w = threadIdx.x >> 6, lane = threadIdx.x & 63;
    float s = 0.f;
    for (int c = lane; c < 768; c += 64) s += decf(gi[w * 768 + c]) * out_w[c];
    #pragma unroll
    for (int d = 1; d < 64; d <<= 1) s += __shfl_xor(s, d);
    __shared__ float lloss[16];
    if (lane == 0) {
        float z = s + out_b[0];
        out[1 + w] = 1.f / (1.f + expf(-z));
        lloss[w] = fmaxf(z, 0.f) - z * y[w] + log1pf(expf(-fabsf(z)));
    }
    __syncthreads();
    if (threadIdx.x == 0) {
        float L = 0.f;
        for (int g2 = 0; g2 < 16; ++g2) L += lloss[g2];
        out[0] = L * (1.f / 16.f);
    }
}

extern "C" void kernel_launch(void* const* d_in, const int* in_sizes, int n_in,
                              void* d_out, int out_size, void* d_ws, size_t ws_size,
                              hipStream_t stream) {
    const int* word_id   = (const int*)d_in[0];
    const int* topic_id  = (const int*)d_in[1];
    const int* g_word    = (const int*)d_in[2];
    const int* g_topic   = (const int*)d_in[3];
    const int* g_doc     = (const int*)d_in[4];
    const int* src_ww = (const int*)d_in[5];  const int* dst_ww = (const int*)d_in[6];  const int* time_ww = (const int*)d_in[7];
    const int* src_wd = (const int*)d_in[8];  const int* dst_wd = (const int*)d_in[9];  const int* time_wd = (const int*)d_in[10];
    const int* src_wt = (const int*)d_in[11]; const int* dst_wt = (const int*)d_in[12]; const int* time_wt = (const int*)d_in[13];
    const int* src_td = (const int*)d_in[14]; const int* dst_td = (const int*)d_in[15]; const int* time_td = (const int*)d_in[16];
    const int* src_tt = (const int*)d_in[17]; const int* dst_tt = (const int*)d_in[18];
    const float* y_data      = (const float*)d_in[19];
    const float* word_embeds = (const float*)d_in[20];
    const float* topic_embeds= (const float*)d_in[21];
    const float* doc_gen     = (const float*)d_in[22];
    const float* adapt_w     = (const float*)d_in[23];
    const float* adapt_b     = (const float*)d_in[24];
    const float* time_tab    = (const float*)d_in[25];
    const float* time_w      = (const float*)d_in[26];
    const float* time_b      = (const float*)d_in[27];
    const float* kW = (const float*)d_in[28];
    const float* qW = (const float*)d_in[29];
    const float* vW = (const float*)d_in[30];
    const float* aW = (const float*)d_in[31];
    const float* kB = (const float*)d_in[32];
    const float* qB = (const float*)d_in[33];
    const float* vB = (const float*)d_in[34];
    const float* aB = (const float*)d_in[35];
    const float* skip = (const float*)d_in[36];
    const float* ln_g = (const float*)d_in[37];
    const float* ln_b = (const float*)d_in[38];
    const float* pri  = (const float*)d_in[39];
    const float* attR = (const float*)d_in[40];
    const float* msgR = (const float*)d_in[41];
    const float* out_w = (const float*)d_in[42];
    const float* out_b = (const float*)d_in[43];

    const int NW = in_sizes[0], NT = in_sizes[1], ND = in_sizes[4];
    const int E_ww = in_sizes[5], E_wd = in_sizes[8], E_wt = in_sizes[11],
              E_td = in_sizes[14], E_tt = in_sizes[17];
    const int nN[3] = {NW, NT, ND};
    const float invNin[3] = {1.f / 3.f, 1.f / 3.f, 1.f / 2.f};

    struct Rel { int e, s, d; const int* src; const int* dst; const int* tim; int E; };
    const Rel rels[8] = {
        {0, 0, 1, src_wt, dst_wt, time_wt, E_wt},
        {1, 0, 2, src_wd, dst_wd, time_wd, E_wd},
        {2, 1, 2, src_td, dst_td, time_td, E_td},
        {3, 1, 1, src_tt, dst_tt, nullptr, E_tt},
        {4, 0, 0, src_ww, dst_ww, time_ww, E_ww},
        {5, 1, 0, dst_wt, src_wt, time_wt, E_wt},
        {6, 2, 1, dst_td, src_td, time_td, E_td},
        {7, 2, 0, dst_wd, src_wd, time_wd, E_wd},
    };

    int relOfs[9]; relOfs[0] = 0;
    int dstBase[8]; int acc = 0;
    for (int r = 0; r < 8; ++r) { relOfs[r + 1] = relOfs[r] + rels[r].E; dstBase[r] = acc; acc += nN[rels[r].d]; }
    const int totE = relOfs[8], totD = acc;

    const int grpRels[3][3] = {{4, 5, 7}, {0, 3, 6}, {1, 2, 0}};
    const int nrG[3] = {3, 3, 2};
    int rowOfsG[3][3], grpRows[3];
    for (int g = 0; g < 3; ++g) {
        int ro = 0;
        for (int j = 0; j < nrG[g]; ++j) { rowOfsG[g][j] = ro; ro += nN[rels[grpRels[g][j]].s]; }
        grpRows[g] = ro;
    }
    int maxGrpRows = 0;
    for (int g = 0; g < 3; ++g) if (grpRows[g] > maxGrpRows) maxGrpRows = grpRows[g];

    int nPad[3], rowOfsT[4];
    rowOfsT[0] = 0;
    for (int i = 0; i < 3; ++i) { nPad[i] = (nN[i] + 63) & ~63; rowOfsT[i + 1] = rowOfsT[i] + nPad[i]; }
    const int totPad = rowOfsT[3];

    float* base = (float*)d_ws;
    size_t off = 0;
    auto take = [&](size_t nElems) { float* p = base + off; off += (nElems + 63) & ~(size_t)63; return p; };
    float* hPbase = take((size_t)totPad * 256);
    unsigned short* hB = (unsigned short*)take((size_t)totPad * 128);
    unsigned short* tB = (unsigned short*)take((size_t)totPad * 128);
    unsigned short* kPb = (unsigned short*)take((size_t)totPad * 128);
    unsigned short* qPb = (unsigned short*)take((size_t)totPad * 128);
    unsigned short* vPb = (unsigned short*)take((size_t)totPad * 128);
    size_t uniFloats = (size_t)maxGrpRows * 256;
    if ((size_t)totPad * 256 > uniFloats) uniFloats = (size_t)totPad * 256;
    float* uni = take(uniFloats);
    unsigned short* kattB = (unsigned short*)uni;
    unsigned short* vmsgB = (unsigned short*)(uni + (size_t)maxGrpRows * 128);
    float* trans = uni;
    unsigned short* WT = (unsigned short*)take((size_t)25 * 32768);
    float* alog = take((size_t)totE * 8);
    float* te7  = take(7 * 32);
    unsigned* gi = (unsigned*)take(16 * 768);
    int* cntAll = (int*)take(totD);
    int* part   = (int*)take(totD);
    int* bsum   = (int*)take(256);
    int* rowptrAll = (int*)take(totD + 1);
    int* curAll = (int*)take(totD);
    int* eidxAll = (int*)take(totE);
    (void)ws_size; (void)n_in; (void)out_size;

    te_kernel<<<1, 256, 0, stream>>>(time_tab, time_w, time_b, te7);
    {
        dim3 g(8, 8, 25);
        wtr_kernel<<<g, 256, 0, stream>>>(adapt_w, kW, qW, vW, aW, WT);
    }
    CsrArgs ca;
    for (int r = 0; r < 8; ++r) { ca.dst[r] = rels[r].dst; ca.dstBase[r] = dstBase[r]; }
    for (int r = 0; r < 9; ++r) ca.relOfs[r] = relOfs[r];
    hipMemsetAsync(cntAll, 0, (size_t)totD * sizeof(int), stream);
    count_all<<<(totE + 255) / 256, 256, 0, stream>>>(ca, cntAll, totE);
    int nb = (totD + 1023) / 1024;
    scan1_k<<<nb, 1024, 0, stream>>>(cntAll, part, bsum, totD);
    scan2_k<<<1, 256, 0, stream>>>(bsum, nb);
    scan3_k<<<(totD + 255) / 256, 256, 0, stream>>>(cntAll, part, bsum, rowptrAll, curAll, totD);
    scatter_all<<<(totE + 255) / 256, 256, 0, stream>>>(ca, curAll, eidxAll, totE);
    gi_init<<<48, 256, 0, stream>>>(gi);

    {
        dim3 g((NW + 63) / 64, 4);
        gemm_init<<<g, 256, 0, stream>>>(word_embeds, word_id, WT, adapt_b, hPbase, hB, NW);
    }
    gather_rows<<<NT, 256, 0, stream>>>(topic_embeds, topic_id,
                                        hPbase + (size_t)rowOfsT[1] * 256,
                                        hB + (size_t)rowOfsT[1] * 256, NT);
    bcast_row<<<ND, 256, 0, stream>>>(doc_gen,
                                      hPbase + (size_t)rowOfsT[2] * 256,
                                      hB + (size_t)rowOfsT[2] * 256, ND);

    Ek1Args e1a[3]; Ek3Args e3a[3];
    int maxE_g[3];
    for (int g = 0; g < 3; ++g) {
        int me = 0;
        for (int j = 0; j < 3; ++j) {
            int jr = (j < nrG[g]) ? grpRels[g][j] : grpRels[g][0];
            const Rel& R = rels[jr];
            e1a[g].src[j] = R.src; e1a[g].dst[j] = R.dst;
            e1a[g].E[j] = (j < nrG[g]) ? R.E : 0;
            e1a[g].eBase[j] = relOfs[jr];
            e1a[g].rowOfs[j] = (j < nrG[g]) ? rowOfsG[g][j] : 0;
            e3a[g].src[j] = R.src; e3a[g].tim[j] = R.tim;
            e3a[g].eBase[j] = relOfs[jr]; e3a[g].dstBase[j] = dstBase[jr];
            e3a[g].rowOfs[j] = (j < nrG[g]) ? rowOfsG[g][j] : 0;
            if (j < nrG[g] && R.E > me) me = R.E;
        }
        e3a[g].nr = nrG[g]; e3a[g].nD = nN[g];
        maxE_g[g] = me;
    }

    GBArgs gb;
    for (int i = 0; i < 4; ++i) gb.rb[i] = rowOfsT[i] / 64;
    for (int i = 0; i < 3; ++i) gb.nLoc[i] = nN[i];
    MLArgs ml;
    for (int i = 0; i < 4; ++i) ml.rowOfs[i] = rowOfsT[i];
    for (int i = 0; i < 3; ++i) ml.nLoc[i] = nN[i];

    const int totBlocks = totPad / 64;
    for (int li = 0; li < LNUM; ++li) {
        gb.li3 = li * 3; ml.li3 = li * 3;
        {
            dim3 g(totBlocks, 2);
            gemm_batch<<<g, 256, 0, stream>>>(hB, WT, 1, 3, kB, qB, vB,
                                              kPb, qPb, vPb, 1, gb);
        }
        for (int g = 0; g < 3; ++g) {
            BdArgs ba;
            int maxRows = 0;
            for (int j = 0; j < 3; ++j) {
                int jr = (j < nrG[g]) ? grpRels[g][j] : grpRels[g][0];
                const Rel& R = rels[jr];
                ba.inK[j] = kPb + (size_t)rowOfsT[R.s] * 256;
                ba.inV[j] = vPb + (size_t)rowOfsT[R.s] * 256;
                ba.RA[j] = attR + ((size_t)li * 8 + R.e) * 8192;
                ba.RM[j] = msgR + ((size_t)li * 8 + R.e) * 8192;
                ba.priP[j] = pri + ((size_t)li * 8 + R.e) * 8;
                ba.rows[j] = (j < nrG[g]) ? nN[R.s] : 0;
                ba.rowOfs[j] = (j < nrG[g]) ? rowOfsG[g][j] : 0;
                if (ba.rows[j] > maxRows) maxRows = ba.rows[j];
            }
            dim3 gbd((maxRows + 127) / 128, 8, 2 * nrG[g]);
            bd_mfma<<<gbd, 256, 0, stream>>>(kattB, vmsgB, ba);
            dim3 g1((maxE_g[g] * 8 + 255) / 256, nrG[g]);
            ek1_group<<<g1, 256, 0, stream>>>(qPb + (size_t)rowOfsT[g] * 256, kattB, alog, e1a[g]);
            ek3_group<<<(nN[g] + 3) / 4, 256, 0, stream>>>(vmsgB, alog, rowptrAll, eidxAll,
                                                           te7, tB + (size_t)rowOfsT[g] * 256,
                                                           invNin[g], e3a[g]);
        }
        {
            dim3 g(totBlocks, 2);
            gemm_batch<<<g, 256, 0, stream>>>(tB, WT, 19, 1, aB, aB, aB,
                                              trans, trans, trans, 0, gb);
        }
        mix_ln_all<<<totPad, 256, 0, stream>>>(hPbase, hB, trans, skip, ln_g, ln_b, ml);
    }

    GmaxArgs ga;
    ga.hp[0] = hPbase + (size_t)rowOfsT[2] * 256; ga.grp[0] = g_doc;   ga.n[0] = ND; ga.colBase[0] = 0;
    ga.hp[1] = hPbase;                             ga.grp[1] = g_word;  ga.n[1] = NW; ga.colBase[1] = 256;
    ga.hp[2] = hPbase + (size_t)rowOfsT[1] * 256; ga.grp[2] = g_topic; ga.n[2] = NT; ga.colBase[2] = 512;
    int maxN = NW > ND ? (NW > NT ? NW : NT) : (ND > NT ? ND : NT);
    dim3 gg((maxN + 63) / 64, 3);
    gmax_all<<<gg, 256, 0, stream>>>(ga, gi);
    final_k<<<1, 1024, 0, stream>>>(gi, out_w, out_b, y_data, (float*)d_out);
}

// Round 14
// 716.958 us; speedup vs baseline: 1.0313x; 1.0313x over previous
//
#include <hip/hip_runtime.h>
#include <hip/hip_bf16.h>
#include <math.h>

#define H 8
#define DK 32
#define NHID 256
#define LNUM 2
#define GNUM 16

typedef float f32x4 __attribute__((ext_vector_type(4)));
typedef short bf16x8 __attribute__((ext_vector_type(8)));
typedef unsigned short u16x8 __attribute__((ext_vector_type(8)));

__device__ __forceinline__ unsigned encf(float f) {
    unsigned u = __float_as_uint(f);
    return (u & 0x80000000u) ? ~u : (u | 0x80000000u);
}
__device__ __forceinline__ float decf(unsigned u) {
    return __uint_as_float((u & 0x80000000u) ? (u ^ 0x80000000u) : ~u);
}
__device__ __forceinline__ float bfd(unsigned short u) {
    return __uint_as_float(((unsigned)u) << 16);
}
__device__ __forceinline__ unsigned short f2bf(float x) {
    __hip_bfloat16 b = __float2bfloat16(x);
    return *reinterpret_cast<unsigned short*>(&b);
}

// Panel swizzle: 64-row panels, LDS-image layout. kb = byte offset in 512B row.
#define APAN2(row, kb) ((((kb) >> 7) << 12) + ((row) << 6) + ((((kb) & 127) ^ (((row) & 7) << 4)) >> 1))
__device__ __forceinline__ size_t swzA(int row, int col /*elem*/) {
    return (((size_t)(row >> 6)) << 14) + (size_t)APAN2(row & 63, col * 2);
}
#define SWZB(row, kb)  (((row) << 6) + ((((kb) ^ (((row) & 7) << 4))) >> 1))

// ---------- by-value arg structs ----------
struct CsrArgs { const int* dst[8]; int relOfs[9]; int dstBase[8]; };
struct BdArgs  { const unsigned short* inK[3]; const unsigned short* inV[3];
                 const float* RA[3]; const float* RM[3]; const float* priP[3];
                 int rows[3]; int rowOfs[3]; };
struct Ek1Args { const int* src[3]; const int* dst[3]; int E[3]; int eBase[3]; int rowOfs[3]; };
struct Ek3Args { const int* src[3]; const int* tim[3]; int eBase[3]; int dstBase[3];
                 int rowOfs[3]; int nr; int nD; };
struct GmaxArgs{ const float* hp[3]; const int* grp[3]; int n[3]; int colBase[3]; };
struct GBArgs  { int rb[4]; int nLoc[3]; int li3; };
struct MLArgs  { int rowOfs[4]; int nLoc[3]; int li3; };

// ---------- temporal encoding table ----------
__global__ void te_kernel(const float* __restrict__ time_tab, const float* __restrict__ time_w,
                          const float* __restrict__ time_b, float* __restrict__ te7) {
    int t = threadIdx.x >> 5, j = threadIdx.x & 31;
    if (t < 7) {
        float s = time_b[j];
        #pragma unroll
        for (int i = 0; i < 32; ++i) s += time_tab[t * 32 + i] * time_w[i * 32 + j];
        te7[t * 32 + j] = s;
    }
}

__global__ void gather_rows(const float* __restrict__ emb, const int* __restrict__ idx,
                            float* __restrict__ out, unsigned short* __restrict__ outB, int n) {
    int row = blockIdx.x, c = threadIdx.x;
    if (row < n) {
        float v = emb[(size_t)idx[row] * 256 + c];
        out[(size_t)row * 256 + c] = v;
        outB[swzA(row, c)] = f2bf(v);
    }
}

__global__ void bcast_row(const float* __restrict__ src, float* __restrict__ out,
                          unsigned short* __restrict__ outB, int n) {
    int row = blockIdx.x, c = threadIdx.x;
    if (row < n) {
        float v = src[c];
        out[(size_t)row * 256 + c] = v;
        outB[swzA(row, c)] = f2bf(v);
    }
}

// ---------- weight transpose+bf16: tile-linear pre-swizzled chunks ----------
// WT[z] elem (col,k) -> ((col>>6)*4 + (k>>6))*4096 + SWZB(col&63, (k&63)*2)
__global__ __launch_bounds__(256) void wtr_kernel(
    const float* __restrict__ adaptW, const float* __restrict__ kW, const float* __restrict__ qW,
    const float* __restrict__ vW, const float* __restrict__ aW, unsigned short* __restrict__ WT) {
    int z = blockIdx.z;
    const float* src;
    if (z == 0) src = adaptW;
    else if (z < 7)  src = kW + (size_t)(z - 1) * 65536;
    else if (z < 13) src = qW + (size_t)(z - 7) * 65536;
    else if (z < 19) src = vW + (size_t)(z - 13) * 65536;
    else             src = aW + (size_t)(z - 19) * 65536;
    unsigned short* dst = WT + (size_t)z * 65536;
    __shared__ float tile[32][33];
    int tx = threadIdx.x & 31, ty = threadIdx.x >> 5;
    int kb = blockIdx.x * 32, cb = blockIdx.y * 32;
    #pragma unroll
    for (int i = 0; i < 4; ++i)
        tile[ty + i * 8][tx] = src[(size_t)(kb + ty + i * 8) * 256 + cb + tx];
    __syncthreads();
    #pragma unroll
    for (int i = 0; i < 4; ++i) {
        int col = cb + ty + i * 8, k = kb + tx;
        dst[((col >> 6) * 4 + (k >> 6)) * 4096 + SWZB(col & 63, (k & 63) * 2)] =
            f2bf(tile[tx][ty + i * 8]);
    }
}

// ---------- batched MFMA GEMM over concat rows, 64-col blocks, chunk-linear B dbuf ----------
// grid (totRowBlocks, 4 colTiles). Wave wv: rows (wv&1)*32, cols (wv>>1)*32. acc 2x2.
__global__ __launch_bounds__(256) void gemm_batch(
    const unsigned short* __restrict__ Apan,
    const unsigned short* __restrict__ WT, int wBase, int nz,
    const float* __restrict__ b0, const float* __restrict__ b1, const float* __restrict__ b2,
    void* __restrict__ o0, void* __restrict__ o1, void* __restrict__ o2,
    int outBf16, GBArgs ga)
{
    __shared__ unsigned short As[64 * 256];     // 32 KB
    __shared__ unsigned short Bs[2][4096];      // 2 x 8 KB
    const int tid = threadIdx.x;
    const int lane = tid & 63, wv = tid >> 6;
    const int b = blockIdx.x;
    const int t = (b >= ga.rb[2]) ? 2 : ((b >= ga.rb[1]) ? 1 : 0);
    const int nLoc = ga.nLoc[t];
    const int locRowBase = (b - ga.rb[t]) * 64;
    const int cb6 = blockIdx.y;                 // 64-col tile
    const int mBase = wBase + ga.li3 + t;
    // ---- stage A panel (linear copy) ----
    {
        const u16x8* src = reinterpret_cast<const u16x8*>(Apan + (((size_t)b) << 14));
        u16x8* dst = reinterpret_cast<u16x8*>(As);
        #pragma unroll
        for (int it = 0; it < 8; ++it)
            dst[it * 256 + tid] = src[it * 256 + tid];
    }
    const int fr = lane & 15, fg = lane >> 4;
    const int wrow = (wv & 1) * 32, wcol = (wv >> 1) * 32;
    const int nt = nz * 4;
    // prologue: stage step-0 chunk (contiguous copy)
    {
        const u16x8* src = reinterpret_cast<const u16x8*>(WT + (size_t)mBase * 65536 + (size_t)(cb6 * 4 + 0) * 4096);
        u16x8* dst = reinterpret_cast<u16x8*>(Bs[0]);
        dst[tid] = src[tid];
        dst[tid + 256] = src[tid + 256];
    }
    __syncthreads();

    f32x4 acc[2][2];
    #pragma unroll
    for (int m = 0; m < 2; ++m)
        #pragma unroll
        for (int nn = 0; nn < 2; ++nn) acc[m][nn] = 0.f;

    for (int tt2 = 0; tt2 < nt; ++tt2) {
        const int cur = tt2 & 1;
        const int ks = tt2 & 3, z = tt2 >> 2;
        u16x8 w0, w1;
        const bool pf = (tt2 + 1 < nt);
        if (pf) {
            int tn = tt2 + 1;
            const u16x8* src = reinterpret_cast<const u16x8*>(
                WT + (size_t)(mBase + (tn >> 2) * 6) * 65536 + (size_t)(cb6 * 4 + (tn & 3)) * 4096);
            w0 = src[tid];
            w1 = src[tid + 256];
        }
        #pragma unroll
        for (int kk = 0; kk < 2; ++kk) {
            bf16x8 af0 = *reinterpret_cast<bf16x8*>(&As[APAN2(wrow + fr,      ks * 128 + kk * 64 + fg * 16)]);
            bf16x8 af1 = *reinterpret_cast<bf16x8*>(&As[APAN2(wrow + 16 + fr, ks * 128 + kk * 64 + fg * 16)]);
            bf16x8 bf0 = *reinterpret_cast<bf16x8*>(&Bs[cur][SWZB(wcol + fr,      kk * 64 + fg * 16)]);
            bf16x8 bf1 = *reinterpret_cast<bf16x8*>(&Bs[cur][SWZB(wcol + 16 + fr, kk * 64 + fg * 16)]);
            acc[0][0] = __builtin_amdgcn_mfma_f32_16x16x32_bf16(af0, bf0, acc[0][0], 0, 0, 0);
            acc[0][1] = __builtin_amdgcn_mfma_f32_16x16x32_bf16(af0, bf1, acc[0][1], 0, 0, 0);
            acc[1][0] = __builtin_amdgcn_mfma_f32_16x16x32_bf16(af1, bf0, acc[1][0], 0, 0, 0);
            acc[1][1] = __builtin_amdgcn_mfma_f32_16x16x32_bf16(af1, bf1, acc[1][1], 0, 0, 0);
        }
        if (pf) {
            u16x8* dst = reinterpret_cast<u16x8*>(Bs[cur ^ 1]);
            dst[tid] = w0;
            dst[tid + 256] = w1;
        }
        if (ks == 3) {
            const float* biasB = (z == 0) ? b0 : ((z == 1) ? b1 : b2);
            const float* bias = biasB + (size_t)(ga.li3 + t) * 256;
            void* outp = (z == 0) ? o0 : ((z == 1) ? o1 : o2);
            #pragma unroll
            for (int m = 0; m < 2; ++m) {
                #pragma unroll
                for (int r = 0; r < 4; ++r) {
                    int lr = locRowBase + wrow + m * 16 + fg * 4 + r;
                    if (lr >= nLoc) continue;
                    size_t gr = (size_t)b * 64 + wrow + m * 16 + fg * 4 + r;
                    #pragma unroll
                    for (int nn = 0; nn < 2; ++nn) {
                        int gc = cb6 * 64 + wcol + nn * 16 + fr;
                        float v = acc[m][nn][r] + bias[gc];
                        if (outBf16) ((unsigned short*)outp)[gr * 256 + gc] = f2bf(v);
                        else         ((float*)outp)[gr * 256 + gc] = v;
                    }
                }
            }
            #pragma unroll
            for (int m = 0; m < 2; ++m)
                #pragma unroll
                for (int nn = 0; nn < 2; ++nn) acc[m][nn] = 0.f;
        }
        __syncthreads();
    }
}

// ---------- init GEMM (word adapt): f32 gather A, chunk-linear B, 64-col blocks ----------
__global__ __launch_bounds__(256) void gemm_init(
    const float* __restrict__ A, const int* __restrict__ gidx,
    const unsigned short* __restrict__ WT, const float* __restrict__ bias,
    float* __restrict__ outF, unsigned short* __restrict__ dupB, int n)
{
    __shared__ unsigned short As[64 * 256];
    __shared__ unsigned short Bs[2][4096];
    const int tid = threadIdx.x;
    const int lane = tid & 63, wv = tid >> 6;
    const int rowBase = blockIdx.x * 64;
    const int cb6 = blockIdx.y;
    #pragma unroll 4
    for (int it = 0; it < 16; ++it) {
        int row = it * 4 + wv;
        int r = rowBase + row;
        ushort4 p = make_ushort4(0, 0, 0, 0);
        if (r < n) {
            int ar = gidx[r];
            float4 v = *reinterpret_cast<const float4*>(A + (size_t)ar * 256 + lane * 4);
            p.x = f2bf(v.x); p.y = f2bf(v.y); p.z = f2bf(v.z); p.w = f2bf(v.w);
        }
        *reinterpret_cast<ushort4*>(&As[APAN2(row, lane * 8)]) = p;
    }
    const int fr = lane & 15, fg = lane >> 4;
    const int wrow = (wv & 1) * 32, wcol = (wv >> 1) * 32;
    {
        const u16x8* src = reinterpret_cast<const u16x8*>(WT + (size_t)(cb6 * 4 + 0) * 4096);
        u16x8* dst = reinterpret_cast<u16x8*>(Bs[0]);
        dst[tid] = src[tid];
        dst[tid + 256] = src[tid + 256];
    }
    __syncthreads();
    f32x4 acc[2][2];
    #pragma unroll
    for (int m = 0; m < 2; ++m)
        #pragma unroll
        for (int nn = 0; nn < 2; ++nn) acc[m][nn] = 0.f;
    for (int t = 0; t < 4; ++t) {
        const int cur = t & 1;
        u16x8 w0, w1;
        const bool pf = (t + 1 < 4);
        if (pf) {
            const u16x8* src = reinterpret_cast<const u16x8*>(WT + (size_t)(cb6 * 4 + t + 1) * 4096);
            w0 = src[tid];
            w1 = src[tid + 256];
        }
        #pragma unroll
        for (int kk = 0; kk < 2; ++kk) {
            bf16x8 af0 = *reinterpret_cast<bf16x8*>(&As[APAN2(wrow + fr,      t * 128 + kk * 64 + fg * 16)]);
            bf16x8 af1 = *reinterpret_cast<bf16x8*>(&As[APAN2(wrow + 16 + fr, t * 128 + kk * 64 + fg * 16)]);
            bf16x8 bf0 = *reinterpret_cast<bf16x8*>(&Bs[cur][SWZB(wcol + fr,      kk * 64 + fg * 16)]);
            bf16x8 bf1 = *reinterpret_cast<bf16x8*>(&Bs[cur][SWZB(wcol + 16 + fr, kk * 64 + fg * 16)]);
            acc[0][0] = __builtin_amdgcn_mfma_f32_16x16x32_bf16(af0, bf0, acc[0][0], 0, 0, 0);
            acc[0][1] = __builtin_amdgcn_mfma_f32_16x16x32_bf16(af0, bf1, acc[0][1], 0, 0, 0);
            acc[1][0] = __builtin_amdgcn_mfma_f32_16x16x32_bf16(af1, bf0, acc[1][0], 0, 0, 0);
            acc[1][1] = __builtin_amdgcn_mfma_f32_16x16x32_bf16(af1, bf1, acc[1][1], 0, 0, 0);
        }
        if (pf) {
            u16x8* dst = reinterpret_cast<u16x8*>(Bs[cur ^ 1]);
            dst[tid] = w0;
            dst[tid + 256] = w1;
        }
        __syncthreads();
    }
    #pragma unroll
    for (int m = 0; m < 2; ++m) {
        #pragma unroll
        for (int r = 0; r < 4; ++r) {
            int gr = rowBase + wrow + m * 16 + fg * 4 + r;
            if (gr >= n) continue;
            #pragma unroll
            for (int nn = 0; nn < 2; ++nn) {
                int gc = cb6 * 64 + wcol + nn * 16 + fr;
                float v = acc[m][nn][r] + bias[gc];
                outF[(size_t)gr * 256 + gc] = v;
                dupB[swzA(gr, gc)] = f2bf(v);
            }
        }
    }
}

// ---------- MFMA block-diagonal transform ----------
__global__ __launch_bounds__(256) void bd_mfma(
    unsigned short* __restrict__ katt, unsigned short* __restrict__ vmsg, BdArgs A)
{
    const int rr = blockIdx.z >> 1, isV = blockIdx.z & 1;
    const int n = A.rows[rr];
    const int rowBase = blockIdx.x * 128;
    if (rowBase >= n) return;
    const unsigned short* in = isV ? A.inV[rr] : A.inK[rr];
    const float* R = isV ? A.RM[rr] : A.RA[rr];
    unsigned short* out = (isV ? vmsg : katt) + (size_t)A.rowOfs[rr] * 256;
    const int head = blockIdx.y;
    const float oscale = isV ? 1.f : (A.priP[rr][head] * 0.17677669529663687f);
    const int tid = threadIdx.x, lane = tid & 63, wv = tid >> 6;
    const int fr = lane & 15, fg = lane >> 4;
    const float* Rh = R + head * 1024;
    bf16x8 b0, b1;
    #pragma unroll
    for (int j = 0; j < 8; ++j) {
        b0[j] = (short)f2bf(Rh[(fg * 8 + j) * 32 + fr] * oscale);
        b1[j] = (short)f2bf(Rh[(fg * 8 + j) * 32 + 16 + fr] * oscale);
    }
    const int r0 = rowBase + wv * 32 + fr;
    const int r1 = r0 + 16;
    const int rc0 = (r0 < n) ? r0 : n - 1;
    const int rc1 = (r1 < n) ? r1 : n - 1;
    bf16x8 a0 = *reinterpret_cast<const bf16x8*>(in + (size_t)rc0 * 256 + head * 32 + fg * 8);
    bf16x8 a1 = *reinterpret_cast<const bf16x8*>(in + (size_t)rc1 * 256 + head * 32 + fg * 8);
    f32x4 acc00 = 0.f, acc01 = 0.f, acc10 = 0.f, acc11 = 0.f;
    acc00 = __builtin_amdgcn_mfma_f32_16x16x32_bf16(a0, b0, acc00, 0, 0, 0);
    acc01 = __builtin_amdgcn_mfma_f32_16x16x32_bf16(a0, b1, acc01, 0, 0, 0);
    acc10 = __builtin_amdgcn_mfma_f32_16x16x32_bf16(a1, b0, acc10, 0, 0, 0);
    acc11 = __builtin_amdgcn_mfma_f32_16x16x32_bf16(a1, b1, acc11, 0, 0, 0);
    const int colB = head * 32 + fr;
    #pragma unroll
    for (int r = 0; r < 4; ++r) {
        int g0 = rowBase + wv * 32 + fg * 4 + r;
        if (g0 < n) {
            out[(size_t)g0 * 256 + colB]      = f2bf(acc00[r]);
            out[(size_t)g0 * 256 + colB + 16] = f2bf(acc01[r]);
        }
        int g1 = g0 + 16;
        if (g1 < n) {
            out[(size_t)g1 * 256 + colB]      = f2bf(acc10[r]);
            out[(size_t)g1 * 256 + colB + 16] = f2bf(acc11[r]);
        }
    }
}

// ---------- EK1 for a group ----------
__global__ __launch_bounds__(256) void ek1_group(
    const unsigned short* __restrict__ qbuf, const unsigned short* __restrict__ katt,
    float* __restrict__ alog, Ek1Args A)
{
    const int rr = blockIdx.y;
    int gid = blockIdx.x * 256 + threadIdx.x;
    int e = gid >> 3, h = gid & 7;
    if (e >= A.E[rr]) return;
    int s = A.src[rr][e], d = A.dst[rr][e];
    const u16x8* q8 = reinterpret_cast<const u16x8*>(qbuf + (size_t)d * 256 + h * 32);
    const u16x8* k8 = reinterpret_cast<const u16x8*>(katt + ((size_t)(A.rowOfs[rr] + s)) * 256 + h * 32);
    float a = 0.f;
    #pragma unroll
    for (int j = 0; j < 4; ++j) {
        u16x8 qv = q8[j], kv = k8[j];
        #pragma unroll
        for (int m = 0; m < 8; ++m) a += bfd(qv[m]) * bfd(kv[m]);
    }
    alog[(size_t)(A.eBase[rr] + e) * 8 + h] = a;
}

// ---------- EK3: wave per dst, single-pass online softmax, swizzled bf16 out ----------
__global__ __launch_bounds__(256) void ek3_group(
    const unsigned short* __restrict__ vmsg, const float* __restrict__ alog,
    const int* __restrict__ rowptrAll, const int* __restrict__ eidxAll,
    const float* __restrict__ te7, unsigned short* __restrict__ tacc, float outScale, Ek3Args A)
{
    __shared__ float sTe[224];
    if (threadIdx.x < 224) sTe[threadIdx.x] = te7[threadIdx.x];
    __syncthreads();
    int wv = threadIdx.x >> 6, lane = threadIdx.x & 63;
    int d = blockIdx.x * 4 + wv;
    if (d >= A.nD) return;
    const int bl = lane >> 3, hl = lane & 7;
    const int c = lane * 4, hq = lane >> 3;
    float t0 = 0.f, t1 = 0.f, t2 = 0.f, t3 = 0.f;
    for (int rr = 0; rr < A.nr; ++rr) {
        int base = A.dstBase[rr] + d;
        int beg = rowptrAll[base], end = rowptrAll[base + 1];
        if (beg == end) continue;
        const int* srcp = A.src[rr];
        const int* timp = A.tim[rr];
        int eB = A.eBase[rr], rO = A.rowOfs[rr];
        float m = -INFINITY, den = 0.f;
        float a0 = 0.f, a1 = 0.f, a2 = 0.f, a3 = 0.f;
        for (int p0 = beg; p0 < end; p0 += 8) {
            int p = p0 + bl;
            bool valid = p < end;
            int ge = eidxAll[valid ? p : end - 1];
            int le = ge - eB;
            float a = valid ? alog[(size_t)ge * 8 + hl] : -INFINITY;
            int sS = valid ? srcp[le] : 0;
            int tT = (timp && valid) ? timp[le] : 0;
            float bm = a;
            bm = fmaxf(bm, __shfl_xor(bm, 8));
            bm = fmaxf(bm, __shfl_xor(bm, 16));
            bm = fmaxf(bm, __shfl_xor(bm, 32));
            float bmA = __shfl(bm, hq);
            float mN = fmaxf(m, bmA);
            float sc = __expf(m - mN);
            den *= sc; a0 *= sc; a1 *= sc; a2 *= sc; a3 *= sc;
            m = mN;
            float mL = __shfl(mN, hl * 8);
            float ex = valid ? __expf(a - mL) : 0.f;
            float ds = ex;
            ds += __shfl_xor(ds, 8);
            ds += __shfl_xor(ds, 16);
            ds += __shfl_xor(ds, 32);
            den += __shfl(ds, hq);
            int nb = end - p0; if (nb > 8) nb = 8;
            for (int b = 0; b < nb; ++b) {
                float w = __shfl(ex, b * 8 + hq);
                int sB = __shfl(sS, b * 8);
                ushort4 v = *reinterpret_cast<const ushort4*>(vmsg + ((size_t)(rO + sB)) * 256 + c);
                float vx = bfd(v.x), vy = bfd(v.y), vz = bfd(v.z), vw = bfd(v.w);
                if (timp) {
                    int tB = __shfl(tT, b * 8);
                    const float* tp = &sTe[tB * 32 + (c & 31)];
                    vx += tp[0]; vy += tp[1]; vz += tp[2]; vw += tp[3];
                }
                a0 += w * vx; a1 += w * vy; a2 += w * vz; a3 += w * vw;
            }
        }
        float inv = 1.f / fmaxf(den, 1e-9f);
        t0 += fmaxf(a0 * inv, 0.f); t1 += fmaxf(a1 * inv, 0.f);
        t2 += fmaxf(a2 * inv, 0.f); t3 += fmaxf(a3 * inv, 0.f);
    }
    ushort4 o;
    o.x = f2bf(t0 * outScale); o.y = f2bf(t1 * outScale);
    o.z = f2bf(t2 * outScale); o.w = f2bf(t3 * outScale);
    *reinterpret_cast<ushort4*>(tacc + swzA(d, c)) = o;
}

// ---------- fused CSR build ----------
__global__ void count_all(CsrArgs A, int* __restrict__ cnt, int totE) {
    int gid = blockIdx.x * 256 + threadIdx.x;
    if (gid >= totE) return;
    int r = 0;
    while (gid >= A.relOfs[r + 1]) ++r;
    int e = gid - A.relOfs[r];
    atomicAdd(&cnt[A.dstBase[r] + A.dst[r][e]], 1);
}
__global__ __launch_bounds__(1024) void scan1_k(const int* __restrict__ cnt, int* __restrict__ part,
                                                int* __restrict__ bsum, int n) {
    __shared__ int buf[1024];
    int tid = threadIdx.x, gid = blockIdx.x * 1024 + tid;
    int x = (gid < n) ? cnt[gid] : 0;
    buf[tid] = x; __syncthreads();
    for (int off = 1; off < 1024; off <<= 1) {
        int y = (tid >= off) ? buf[tid - off] : 0;
        __syncthreads();
        buf[tid] += y;
        __syncthreads();
    }
    if (gid < n) part[gid] = buf[tid];
    if (tid == 1023) bsum[blockIdx.x] = buf[1023];
}
__global__ __launch_bounds__(256) void scan2_k(int* __restrict__ bsum, int nb) {
    __shared__ int buf[256];
    int tid = threadIdx.x;
    buf[tid] = (tid < nb) ? bsum[tid] : 0;
    __syncthreads();
    for (int off = 1; off < 256; off <<= 1) {
        int y = (tid >= off) ? buf[tid - off] : 0;
        __syncthreads();
        buf[tid] += y;
        __syncthreads();
    }
    if (tid < nb) bsum[tid] = buf[tid];
}
__global__ void scan3_k(const int* __restrict__ cnt, const int* __restrict__ part,
                        const int* __restrict__ bsum, int* __restrict__ rowptr,
                        int* __restrict__ cur, int n) {
    int gid = blockIdx.x * 256 + threadIdx.x;
    if (gid < n) {
        int b = gid >> 10;
        int add = (b > 0) ? bsum[b - 1] : 0;
        int inc = part[gid] + add;
        rowptr[gid + 1] = inc;
        cur[gid] = inc - cnt[gid];
    }
    if (gid == 0) rowptr[0] = 0;
}
__global__ void scatter_all(CsrArgs A, int* __restrict__ cur, int* __restrict__ eidx, int totE) {
    int gid = blockIdx.x * 256 + threadIdx.x;
    if (gid >= totE) return;
    int r = 0;
    while (gid >= A.relOfs[r + 1]) ++r;
    int e = gid - A.relOfs[r];
    int p = atomicAdd(&cur[A.dstBase[r] + A.dst[r][e]], 1);
    eidx[p] = gid;
}

// ---------- merged skip-mix + layernorm over concat rows ----------
__global__ __launch_bounds__(256) void mix_ln_all(
    float* __restrict__ h, unsigned short* __restrict__ hB, const float* __restrict__ trans,
    const float* __restrict__ skipP, const float* __restrict__ g, const float* __restrict__ b,
    MLArgs M)
{
    int row = blockIdx.x;
    int t = (row >= M.rowOfs[2]) ? 2 : ((row >= M.rowOfs[1]) ? 1 : 0);
    int d = row - M.rowOfs[t];
    if (d >= M.nLoc[t]) return;
    int j = M.li3 + t;
    int c = threadIdx.x;
    float alpha = 1.f / (1.f + expf(-skipP[j]));
    size_t off = (size_t)row * 256 + c;
    float o = trans[off] * alpha + h[off] * (1.f - alpha);
    float s = o, ss = o * o;
    #pragma unroll
    for (int dd = 1; dd < 64; dd <<= 1) { s += __shfl_xor(s, dd); ss += __shfl_xor(ss, dd); }
    __shared__ float rS[4], rSS[4];
    int w = threadIdx.x >> 6, lane = threadIdx.x & 63;
    if (lane == 0) { rS[w] = s; rSS[w] = ss; }
    __syncthreads();
    float S = rS[0] + rS[1] + rS[2] + rS[3];
    float SS = rSS[0] + rSS[1] + rSS[2] + rSS[3];
    float mean = S * (1.f / 256.f);
    float var = fmaxf(SS * (1.f / 256.f) - mean * mean, 0.f);
    float rs = rsqrtf(var + 1e-5f);
    float v = (o - mean) * rs * g[(size_t)j * 256 + c] + b[(size_t)j * 256 + c];
    h[off] = v;
    hB[swzA(row, c)] = f2bf(v);
}

// ---------- group max ----------
__global__ __launch_bounds__(256) void gmax_all(GmaxArgs A, unsigned* __restrict__ gi) {
    int ty = blockIdx.y;
    int n = A.n[ty];
    int r0 = blockIdx.x * 64;
    if (r0 >= n) return;
    int col = threadIdx.x;
    const float* hp = A.hp[ty];
    const int* grp = A.grp[ty];
    int cbase = A.colBase[ty];
    int rend = (r0 + 64 < n) ? r0 + 64 : n;
    int cur = grp[r0];
    float m = -INFINITY;
    for (int r = r0; r < rend; ++r) {
        int g = grp[r];
        if (g != cur) {
            atomicMax(&gi[cur * 768 + cbase + col], encf(m));
            cur = g; m = -INFINITY;
        }
        m = fmaxf(m, hp[(size_t)r * 256 + col]);
    }
    atomicMax(&gi[cur * 768 + cbase + col], encf(m));
}

__global__ void gi_init(unsigned* __restrict__ gi) {
    int i = blockIdx.x * 256 + threadIdx.x;
    if (i < 16 * 768) gi[i] = 0x007FFFFFu;
}

// ---------- final ----------
__global__ __launch_bounds__(1024) void final_k(const unsigned* __restrict__ gi,
                                                const float* __restrict__ out_w,
                                                const float* __restrict__ out_b,
                                                const float* __restrict__ y,
                                                float* __restrict__ out) {
    int w = threadIdx.x >> 6, lane = threadIdx.x & 63;
    float s = 0.f;
    for (int c = lane; c < 768; c += 64) s += decf(gi[w * 768 + c]) * out_w[c];
    #pragma unroll
    for (int d = 1; d < 64; d <<= 1) s += __shfl_xor(s, d);
    __shared__ float lloss[16];
    if (lane == 0) {
        float z = s + out_b[0];
        out[1 + w] = 1.f / (1.f + expf(-z));
        lloss[w] = fmaxf(z, 0.f) - z * y[w] + log1pf(expf(-fabsf(z)));
    }
    __syncthreads();
    if (threadIdx.x == 0) {
        float L = 0.f;
        for (int g2 = 0; g2 < 16; ++g2) L += lloss[g2];
        out[0] = L * (1.f / 16.f);
    }
}

extern "C" void kernel_launch(void* const* d_in, const int* in_sizes, int n_in,
                              void* d_out, int out_size, void* d_ws, size_t ws_size,
                              hipStream_t stream) {
    const int* word_id   = (const int*)d_in[0];
    const int* topic_id  = (const int*)d_in[1];
    const int* g_word    = (const int*)d_in[2];
    const int* g_topic   = (const int*)d_in[3];
    const int* g_doc     = (const int*)d_in[4];
    const int* src_ww = (const int*)d_in[5];  const int* dst_ww = (const int*)d_in[6];  const int* time_ww = (const int*)d_in[7];
    const int* src_wd = (const int*)d_in[8];  const int* dst_wd = (const int*)d_in[9];  const int* time_wd = (const int*)d_in[10];
    const int* src_wt = (const int*)d_in[11]; const int* dst_wt = (const int*)d_in[12]; const int* time_wt = (const int*)d_in[13];
    const int* src_td = (const int*)d_in[14]; const int* dst_td = (const int*)d_in[15]; const int* time_td = (const int*)d_in[16];
    const int* src_tt = (const int*)d_in[17]; const int* dst_tt = (const int*)d_in[18];
    const float* y_data      = (const float*)d_in[19];
    const float* word_embeds = (const float*)d_in[20];
    const float* topic_embeds= (const float*)d_in[21];
    const float* doc_gen     = (const float*)d_in[22];
    const float* adapt_w     = (const float*)d_in[23];
    const float* adapt_b     = (const float*)d_in[24];
    const float* time_tab    = (const float*)d_in[25];
    const float* time_w      = (const float*)d_in[26];
    const float* time_b      = (const float*)d_in[27];
    const float* kW = (const float*)d_in[28];
    const float* qW = (const float*)d_in[29];
    const float* vW = (const float*)d_in[30];
    const float* aW = (const float*)d_in[31];
    const float* kB = (const float*)d_in[32];
    const float* qB = (const float*)d_in[33];
    const float* vB = (const float*)d_in[34];
    const float* aB = (const float*)d_in[35];
    const float* skip = (const float*)d_in[36];
    const float* ln_g = (const float*)d_in[37];
    const float* ln_b = (const float*)d_in[38];
    const float* pri  = (const float*)d_in[39];
    const float* attR = (const float*)d_in[40];
    const float* msgR = (const float*)d_in[41];
    const float* out_w = (const float*)d_in[42];
    const float* out_b = (const float*)d_in[43];

    const int NW = in_sizes[0], NT = in_sizes[1], ND = in_sizes[4];
    const int E_ww = in_sizes[5], E_wd = in_sizes[8], E_wt = in_sizes[11],
              E_td = in_sizes[14], E_tt = in_sizes[17];
    const int nN[3] = {NW, NT, ND};
    const float invNin[3] = {1.f / 3.f, 1.f / 3.f, 1.f / 2.f};

    struct Rel { int e, s, d; const int* src; const int* dst; const int* tim; int E; };
    const Rel rels[8] = {
        {0, 0, 1, src_wt, dst_wt, time_wt, E_wt},
        {1, 0, 2, src_wd, dst_wd, time_wd, E_wd},
        {2, 1, 2, src_td, dst_td, time_td, E_td},
        {3, 1, 1, src_tt, dst_tt, nullptr, E_tt},
        {4, 0, 0, src_ww, dst_ww, time_ww, E_ww},
        {5, 1, 0, dst_wt, src_wt, time_wt, E_wt},
        {6, 2, 1, dst_td, src_td, time_td, E_td},
        {7, 2, 0, dst_wd, src_wd, time_wd, E_wd},
    };

    int relOfs[9]; relOfs[0] = 0;
    int dstBase[8]; int acc = 0;
    for (int r = 0; r < 8; ++r) { relOfs[r + 1] = relOfs[r] + rels[r].E; dstBase[r] = acc; acc += nN[rels[r].d]; }
    const int totE = relOfs[8], totD = acc;

    const int grpRels[3][3] = {{4, 5, 7}, {0, 3, 6}, {1, 2, 0}};
    const int nrG[3] = {3, 3, 2};
    int rowOfsG[3][3], grpRows[3];
    for (int g = 0; g < 3; ++g) {
        int ro = 0;
        for (int j = 0; j < nrG[g]; ++j) { rowOfsG[g][j] = ro; ro += nN[rels[grpRels[g][j]].s]; }
        grpRows[g] = ro;
    }
    int maxGrpRows = 0;
    for (int g = 0; g < 3; ++g) if (grpRows[g] > maxGrpRows) maxGrpRows = grpRows[g];

    int nPad[3], rowOfsT[4];
    rowOfsT[0] = 0;
    for (int i = 0; i < 3; ++i) { nPad[i] = (nN[i] + 63) & ~63; rowOfsT[i + 1] = rowOfsT[i] + nPad[i]; }
    const int totPad = rowOfsT[3];

    float* base = (float*)d_ws;
    size_t off = 0;
    auto take = [&](size_t nElems) { float* p = base + off; off += (nElems + 63) & ~(size_t)63; return p; };
    float* hPbase = take((size_t)totPad * 256);
    unsigned short* hB = (unsigned short*)take((size_t)totPad * 128);
    unsigned short* tB = (unsigned short*)take((size_t)totPad * 128);
    unsigned short* kPb = (unsigned short*)take((size_t)totPad * 128);
    unsigned short* qPb = (unsigned short*)take((size_t)totPad * 128);
    unsigned short* vPb = (unsigned short*)take((size_t)totPad * 128);
    size_t uniFloats = (size_t)maxGrpRows * 256;
    if ((size_t)totPad * 256 > uniFloats) uniFloats = (size_t)totPad * 256;
    float* uni = take(uniFloats);
    unsigned short* kattB = (unsigned short*)uni;
    unsigned short* vmsgB = (unsigned short*)(uni + (size_t)maxGrpRows * 128);
    float* trans = uni;
    unsigned short* WT = (unsigned short*)take((size_t)25 * 32768);
    float* alog = take((size_t)totE * 8);
    float* te7  = take(7 * 32);
    unsigned* gi = (unsigned*)take(16 * 768);
    int* cntAll = (int*)take(totD);
    int* part   = (int*)take(totD);
    int* bsum   = (int*)take(256);
    int* rowptrAll = (int*)take(totD + 1);
    int* curAll = (int*)take(totD);
    int* eidxAll = (int*)take(totE);
    (void)ws_size; (void)n_in; (void)out_size;

    te_kernel<<<1, 256, 0, stream>>>(time_tab, time_w, time_b, te7);
    {
        dim3 g(8, 8, 25);
        wtr_kernel<<<g, 256, 0, stream>>>(adapt_w, kW, qW, vW, aW, WT);
    }
    CsrArgs ca;
    for (int r = 0; r < 8; ++r) { ca.dst[r] = rels[r].dst; ca.dstBase[r] = dstBase[r]; }
    for (int r = 0; r < 9; ++r) ca.relOfs[r] = relOfs[r];
    hipMemsetAsync(cntAll, 0, (size_t)totD * sizeof(int), stream);
    count_all<<<(totE + 255) / 256, 256, 0, stream>>>(ca, cntAll, totE);
    int nb = (totD + 1023) / 1024;
    scan1_k<<<nb, 1024, 0, stream>>>(cntAll, part, bsum, totD);
    scan2_k<<<1, 256, 0, stream>>>(bsum, nb);
    scan3_k<<<(totD + 255) / 256, 256, 0, stream>>>(cntAll, part, bsum, rowptrAll, curAll, totD);
    scatter_all<<<(totE + 255) / 256, 256, 0, stream>>>(ca, curAll, eidxAll, totE);
    gi_init<<<48, 256, 0, stream>>>(gi);

    {
        dim3 g((NW + 63) / 64, 4);
        gemm_init<<<g, 256, 0, stream>>>(word_embeds, word_id, WT, adapt_b, hPbase, hB, NW);
    }
    gather_rows<<<NT, 256, 0, stream>>>(topic_embeds, topic_id,
                                        hPbase + (size_t)rowOfsT[1] * 256,
                                        hB + (size_t)rowOfsT[1] * 256, NT);
    bcast_row<<<ND, 256, 0, stream>>>(doc_gen,
                                      hPbase + (size_t)rowOfsT[2] * 256,
                                      hB + (size_t)rowOfsT[2] * 256, ND);

    Ek1Args e1a[3]; Ek3Args e3a[3];
    int maxE_g[3];
    for (int g = 0; g < 3; ++g) {
        int me = 0;
        for (int j = 0; j < 3; ++j) {
            int jr = (j < nrG[g]) ? grpRels[g][j] : grpRels[g][0];
            const Rel& R = rels[jr];
            e1a[g].src[j] = R.src; e1a[g].dst[j] = R.dst;
            e1a[g].E[j] = (j < nrG[g]) ? R.E : 0;
            e1a[g].eBase[j] = relOfs[jr];
            e1a[g].rowOfs[j] = (j < nrG[g]) ? rowOfsG[g][j] : 0;
            e3a[g].src[j] = R.src; e3a[g].tim[j] = R.tim;
            e3a[g].eBase[j] = relOfs[jr]; e3a[g].dstBase[j] = dstBase[jr];
            e3a[g].rowOfs[j] = (j < nrG[g]) ? rowOfsG[g][j] : 0;
            if (j < nrG[g] && R.E > me) me = R.E;
        }
        e3a[g].nr = nrG[g]; e3a[g].nD = nN[g];
        maxE_g[g] = me;
    }

    GBArgs gb;
    for (int i = 0; i < 4; ++i) gb.rb[i] = rowOfsT[i] / 64;
    for (int i = 0; i < 3; ++i) gb.nLoc[i] = nN[i];
    MLArgs ml;
    for (int i = 0; i < 4; ++i) ml.rowOfs[i] = rowOfsT[i];
    for (int i = 0; i < 3; ++i) ml.nLoc[i] = nN[i];

    const int totBlocks = totPad / 64;
    for (int li = 0; li < LNUM; ++li) {
        gb.li3 = li * 3; ml.li3 = li * 3;
        {
            dim3 g(totBlocks, 4);
            gemm_batch<<<g, 256, 0, stream>>>(hB, WT, 1, 3, kB, qB, vB,
                                              kPb, qPb, vPb, 1, gb);
        }
        for (int g = 0; g < 3; ++g) {
            BdArgs ba;
            int maxRows = 0;
            for (int j = 0; j < 3; ++j) {
                int jr = (j < nrG[g]) ? grpRels[g][j] : grpRels[g][0];
                const Rel& R = rels[jr];
                ba.inK[j] = kPb + (size_t)rowOfsT[R.s] * 256;
                ba.inV[j] = vPb + (size_t)rowOfsT[R.s] * 256;
                ba.RA[j] = attR + ((size_t)li * 8 + R.e) * 8192;
                ba.RM[j] = msgR + ((size_t)li * 8 + R.e) * 8192;
                ba.priP[j] = pri + ((size_t)li * 8 + R.e) * 8;
                ba.rows[j] = (j < nrG[g]) ? nN[R.s] : 0;
                ba.rowOfs[j] = (j < nrG[g]) ? rowOfsG[g][j] : 0;
                if (ba.rows[j] > maxRows) maxRows = ba.rows[j];
            }
            dim3 gbd((maxRows + 127) / 128, 8, 2 * nrG[g]);
            bd_mfma<<<gbd, 256, 0, stream>>>(kattB, vmsgB, ba);
            dim3 g1((maxE_g[g] * 8 + 255) / 256, nrG[g]);
            ek1_group<<<g1, 256, 0, stream>>>(qPb + (size_t)rowOfsT[g] * 256, kattB, alog, e1a[g]);
            ek3_group<<<(nN[g] + 3) / 4, 256, 0, stream>>>(vmsgB, alog, rowptrAll, eidxAll,
                                                           te7, tB + (size_t)rowOfsT[g] * 256,
                                                           invNin[g], e3a[g]);
        }
        {
            dim3 g(totBlocks, 4);
            gemm_batch<<<g, 256, 0, stream>>>(tB, WT, 19, 1, aB, aB, aB,
                                              trans, trans, trans, 0, gb);
        }
        mix_ln_all<<<totPad, 256, 0, stream>>>(hPbase, hB, trans, skip, ln_g, ln_b, ml);
    }

    GmaxArgs ga;
    ga.hp[0] = hPbase + (size_t)rowOfsT[2] * 256; ga.grp[0] = g_doc;   ga.n[0] = ND; ga.colBase[0] = 0;
    ga.hp[1] = hPbase;                             ga.grp[1] = g_word;  ga.n[1] = NW; ga.colBase[1] = 256;
    ga.hp[2] = hPbase + (size_t)rowOfsT[1] * 256; ga.grp[2] = g_topic; ga.n[2] = NT; ga.colBase[2] = 512;
    int maxN = NW > ND ? (NW > NT ? NW : NT) : (ND > NT ? ND : NT);
    dim3 gg((maxN + 63) / 64, 3);
    gmax_all<<<gg, 256, 0, stream>>>(ga, gi);
    final_k<<<1, 1024, 0, stream>>>(gi, out_w, out_b, y_data, (float*)d_out);
}

// Round 16
// 676.366 us; speedup vs baseline: 1.0932x; 1.0600x over previous
//
#include <hip/hip_runtime.h>
#include <hip/hip_bf16.h>
#include <math.h>

#define H 8
#define DK 32
#define NHID 256
#define LNUM 2
#define GNUM 16

typedef float f32x4 __attribute__((ext_vector_type(4)));
typedef short bf16x8 __attribute__((ext_vector_type(8)));
typedef unsigned short u16x8 __attribute__((ext_vector_type(8)));

__device__ __forceinline__ unsigned encf(float f) {
    unsigned u = __float_as_uint(f);
    return (u & 0x80000000u) ? ~u : (u | 0x80000000u);
}
__device__ __forceinline__ float decf(unsigned u) {
    return __uint_as_float((u & 0x80000000u) ? (u ^ 0x80000000u) : ~u);
}
__device__ __forceinline__ float bfd(unsigned short u) {
    return __uint_as_float(((unsigned)u) << 16);
}
__device__ __forceinline__ unsigned short f2bf(float x) {
    __hip_bfloat16 b = __float2bfloat16(x);
    return *reinterpret_cast<unsigned short*>(&b);
}

// Panel swizzle: 64-row panels, LDS-image layout. kb = byte offset in 512B row.
#define APAN2(row, kb) ((((kb) >> 7) << 12) + ((row) << 6) + ((((kb) & 127) ^ (((row) & 7) << 4)) >> 1))
__device__ __forceinline__ size_t swzA(int row, int col /*elem*/) {
    return (((size_t)(row >> 6)) << 14) + (size_t)APAN2(row & 63, col * 2);
}
#define SWZB(row, kb)  (((row) << 6) + ((((kb) ^ (((row) & 7) << 4))) >> 1))

// ---------- by-value arg structs ----------
struct CsrArgs  { const int* dst[8]; int relOfs[9]; int dstBase[8]; };
struct BdAllArgs{ int rows[8]; int srcOfs[8]; int outOfs[8]; };
struct Ek1AllArgs{ const int* src[8]; const int* dst[8]; int E[8]; int eBase[8];
                   int kOfs[8]; int qOfs[8]; };
struct Ek3AllArgs{ const int* src[8]; const int* tim[8]; int eBase[8]; int dstBase[8];
                   int vOfs[8]; int typeRel[9]; int nrT[3]; int cumN[4]; int tOfs[3];
                   float oScale[3]; };
struct GmaxArgs { const float* hp[3]; const int* grp[3]; int n[3]; int colBase[3]; };
struct GBArgs   { int rb[4]; int nLoc[3]; int li3; };
struct MLArgs   { int rowOfs[4]; int nLoc[3]; int li3; };

// ---------- temporal encoding table ----------
__global__ void te_kernel(const float* __restrict__ time_tab, const float* __restrict__ time_w,
                          const float* __restrict__ time_b, float* __restrict__ te7) {
    int t = threadIdx.x >> 5, j = threadIdx.x & 31;
    if (t < 7) {
        float s = time_b[j];
        #pragma unroll
        for (int i = 0; i < 32; ++i) s += time_tab[t * 32 + i] * time_w[i * 32 + j];
        te7[t * 32 + j] = s;
    }
}

__global__ void gather_rows(const float* __restrict__ emb, const int* __restrict__ idx,
                            float* __restrict__ out, unsigned short* __restrict__ outB, int n) {
    int row = blockIdx.x, c = threadIdx.x;
    if (row < n) {
        float v = emb[(size_t)idx[row] * 256 + c];
        out[(size_t)row * 256 + c] = v;
        outB[swzA(row, c)] = f2bf(v);
    }
}

__global__ void bcast_row(const float* __restrict__ src, float* __restrict__ out,
                          unsigned short* __restrict__ outB, int n) {
    int row = blockIdx.x, c = threadIdx.x;
    if (row < n) {
        float v = src[c];
        out[(size_t)row * 256 + c] = v;
        outB[swzA(row, c)] = f2bf(v);
    }
}

// ---------- weight transpose+bf16: tile-linear pre-swizzled chunks ----------
__global__ __launch_bounds__(256) void wtr_kernel(
    const float* __restrict__ adaptW, const float* __restrict__ kW, const float* __restrict__ qW,
    const float* __restrict__ vW, const float* __restrict__ aW, unsigned short* __restrict__ WT) {
    int z = blockIdx.z;
    const float* src;
    if (z == 0) src = adaptW;
    else if (z < 7)  src = kW + (size_t)(z - 1) * 65536;
    else if (z < 13) src = qW + (size_t)(z - 7) * 65536;
    else if (z < 19) src = vW + (size_t)(z - 13) * 65536;
    else             src = aW + (size_t)(z - 19) * 65536;
    unsigned short* dst = WT + (size_t)z * 65536;
    __shared__ float tile[32][33];
    int tx = threadIdx.x & 31, ty = threadIdx.x >> 5;
    int kb = blockIdx.x * 32, cb = blockIdx.y * 32;
    #pragma unroll
    for (int i = 0; i < 4; ++i)
        tile[ty + i * 8][tx] = src[(size_t)(kb + ty + i * 8) * 256 + cb + tx];
    __syncthreads();
    #pragma unroll
    for (int i = 0; i < 4; ++i) {
        int col = cb + ty + i * 8, k = kb + tx;
        dst[((col >> 6) * 4 + (k >> 6)) * 4096 + SWZB(col & 63, (k & 63) * 2)] =
            f2bf(tile[tx][ty + i * 8]);
    }
}

// ---------- batched MFMA GEMM over concat rows, 64-col blocks, chunk-linear B dbuf ----------
__global__ __launch_bounds__(256) void gemm_batch(
    const unsigned short* __restrict__ Apan,
    const unsigned short* __restrict__ WT, int wBase, int nz,
    const float* __restrict__ b0, const float* __restrict__ b1, const float* __restrict__ b2,
    void* __restrict__ o0, void* __restrict__ o1, void* __restrict__ o2,
    int outBf16, GBArgs ga)
{
    __shared__ unsigned short As[64 * 256];
    __shared__ unsigned short Bs[2][4096];
    const int tid = threadIdx.x;
    const int lane = tid & 63, wv = tid >> 6;
    const int b = blockIdx.x;
    const int t = (b >= ga.rb[2]) ? 2 : ((b >= ga.rb[1]) ? 1 : 0);
    const int nLoc = ga.nLoc[t];
    const int locRowBase = (b - ga.rb[t]) * 64;
    const int cb6 = blockIdx.y;
    const int mBase = wBase + ga.li3 + t;
    {
        const u16x8* src = reinterpret_cast<const u16x8*>(Apan + (((size_t)b) << 14));
        u16x8* dst = reinterpret_cast<u16x8*>(As);
        #pragma unroll
        for (int it = 0; it < 8; ++it)
            dst[it * 256 + tid] = src[it * 256 + tid];
    }
    const int fr = lane & 15, fg = lane >> 4;
    const int wrow = (wv & 1) * 32, wcol = (wv >> 1) * 32;
    const int nt = nz * 4;
    {
        const u16x8* src = reinterpret_cast<const u16x8*>(WT + (size_t)mBase * 65536 + (size_t)(cb6 * 4 + 0) * 4096);
        u16x8* dst = reinterpret_cast<u16x8*>(Bs[0]);
        dst[tid] = src[tid];
        dst[tid + 256] = src[tid + 256];
    }
    __syncthreads();

    f32x4 acc[2][2];
    #pragma unroll
    for (int m = 0; m < 2; ++m)
        #pragma unroll
        for (int nn = 0; nn < 2; ++nn) acc[m][nn] = 0.f;

    for (int tt2 = 0; tt2 < nt; ++tt2) {
        const int cur = tt2 & 1;
        const int ks = tt2 & 3, z = tt2 >> 2;
        u16x8 w0, w1;
        const bool pf = (tt2 + 1 < nt);
        if (pf) {
            int tn = tt2 + 1;
            const u16x8* src = reinterpret_cast<const u16x8*>(
                WT + (size_t)(mBase + (tn >> 2) * 6) * 65536 + (size_t)(cb6 * 4 + (tn & 3)) * 4096);
            w0 = src[tid];
            w1 = src[tid + 256];
        }
        #pragma unroll
        for (int kk = 0; kk < 2; ++kk) {
            bf16x8 af0 = *reinterpret_cast<bf16x8*>(&As[APAN2(wrow + fr,      ks * 128 + kk * 64 + fg * 16)]);
            bf16x8 af1 = *reinterpret_cast<bf16x8*>(&As[APAN2(wrow + 16 + fr, ks * 128 + kk * 64 + fg * 16)]);
            bf16x8 bf0 = *reinterpret_cast<bf16x8*>(&Bs[cur][SWZB(wcol + fr,      kk * 64 + fg * 16)]);
            bf16x8 bf1 = *reinterpret_cast<bf16x8*>(&Bs[cur][SWZB(wcol + 16 + fr, kk * 64 + fg * 16)]);
            acc[0][0] = __builtin_amdgcn_mfma_f32_16x16x32_bf16(af0, bf0, acc[0][0], 0, 0, 0);
            acc[0][1] = __builtin_amdgcn_mfma_f32_16x16x32_bf16(af0, bf1, acc[0][1], 0, 0, 0);
            acc[1][0] = __builtin_amdgcn_mfma_f32_16x16x32_bf16(af1, bf0, acc[1][0], 0, 0, 0);
            acc[1][1] = __builtin_amdgcn_mfma_f32_16x16x32_bf16(af1, bf1, acc[1][1], 0, 0, 0);
        }
        if (pf) {
            u16x8* dst = reinterpret_cast<u16x8*>(Bs[cur ^ 1]);
            dst[tid] = w0;
            dst[tid + 256] = w1;
        }
        if (ks == 3) {
            const float* biasB = (z == 0) ? b0 : ((z == 1) ? b1 : b2);
            const float* bias = biasB + (size_t)(ga.li3 + t) * 256;
            void* outp = (z == 0) ? o0 : ((z == 1) ? o1 : o2);
            #pragma unroll
            for (int m = 0; m < 2; ++m) {
                #pragma unroll
                for (int r = 0; r < 4; ++r) {
                    int lr = locRowBase + wrow + m * 16 + fg * 4 + r;
                    if (lr >= nLoc) continue;
                    size_t gr = (size_t)b * 64 + wrow + m * 16 + fg * 4 + r;
                    #pragma unroll
                    for (int nn = 0; nn < 2; ++nn) {
                        int gc = cb6 * 64 + wcol + nn * 16 + fr;
                        float v = acc[m][nn][r] + bias[gc];
                        if (outBf16) ((unsigned short*)outp)[gr * 256 + gc] = f2bf(v);
                        else         ((float*)outp)[gr * 256 + gc] = v;
                    }
                }
            }
            #pragma unroll
            for (int m = 0; m < 2; ++m)
                #pragma unroll
                for (int nn = 0; nn < 2; ++nn) acc[m][nn] = 0.f;
        }
        __syncthreads();
    }
}

// ---------- init GEMM (word adapt) ----------
__global__ __launch_bounds__(256) void gemm_init(
    const float* __restrict__ A, const int* __restrict__ gidx,
    const unsigned short* __restrict__ WT, const float* __restrict__ bias,
    float* __restrict__ outF, unsigned short* __restrict__ dupB, int n)
{
    __shared__ unsigned short As[64 * 256];
    __shared__ unsigned short Bs[2][4096];
    const int tid = threadIdx.x;
    const int lane = tid & 63, wv = tid >> 6;
    const int rowBase = blockIdx.x * 64;
    const int cb6 = blockIdx.y;
    #pragma unroll 4
    for (int it = 0; it < 16; ++it) {
        int row = it * 4 + wv;
        int r = rowBase + row;
        ushort4 p = make_ushort4(0, 0, 0, 0);
        if (r < n) {
            int ar = gidx[r];
            float4 v = *reinterpret_cast<const float4*>(A + (size_t)ar * 256 + lane * 4);
            p.x = f2bf(v.x); p.y = f2bf(v.y); p.z = f2bf(v.z); p.w = f2bf(v.w);
        }
        *reinterpret_cast<ushort4*>(&As[APAN2(row, lane * 8)]) = p;
    }
    const int fr = lane & 15, fg = lane >> 4;
    const int wrow = (wv & 1) * 32, wcol = (wv >> 1) * 32;
    {
        const u16x8* src = reinterpret_cast<const u16x8*>(WT + (size_t)(cb6 * 4 + 0) * 4096);
        u16x8* dst = reinterpret_cast<u16x8*>(Bs[0]);
        dst[tid] = src[tid];
        dst[tid + 256] = src[tid + 256];
    }
    __syncthreads();
    f32x4 acc[2][2];
    #pragma unroll
    for (int m = 0; m < 2; ++m)
        #pragma unroll
        for (int nn = 0; nn < 2; ++nn) acc[m][nn] = 0.f;
    for (int t = 0; t < 4; ++t) {
        const int cur = t & 1;
        u16x8 w0, w1;
        const bool pf = (t + 1 < 4);
        if (pf) {
            const u16x8* src = reinterpret_cast<const u16x8*>(WT + (size_t)(cb6 * 4 + t + 1) * 4096);
            w0 = src[tid];
            w1 = src[tid + 256];
        }
        #pragma unroll
        for (int kk = 0; kk < 2; ++kk) {
            bf16x8 af0 = *reinterpret_cast<bf16x8*>(&As[APAN2(wrow + fr,      t * 128 + kk * 64 + fg * 16)]);
            bf16x8 af1 = *reinterpret_cast<bf16x8*>(&As[APAN2(wrow + 16 + fr, t * 128 + kk * 64 + fg * 16)]);
            bf16x8 bf0 = *reinterpret_cast<bf16x8*>(&Bs[cur][SWZB(wcol + fr,      kk * 64 + fg * 16)]);
            bf16x8 bf1 = *reinterpret_cast<bf16x8*>(&Bs[cur][SWZB(wcol + 16 + fr, kk * 64 + fg * 16)]);
            acc[0][0] = __builtin_amdgcn_mfma_f32_16x16x32_bf16(af0, bf0, acc[0][0], 0, 0, 0);
            acc[0][1] = __builtin_amdgcn_mfma_f32_16x16x32_bf16(af0, bf1, acc[0][1], 0, 0, 0);
            acc[1][0] = __builtin_amdgcn_mfma_f32_16x16x32_bf16(af1, bf0, acc[1][0], 0, 0, 0);
            acc[1][1] = __builtin_amdgcn_mfma_f32_16x16x32_bf16(af1, bf1, acc[1][1], 0, 0, 0);
        }
        if (pf) {
            u16x8* dst = reinterpret_cast<u16x8*>(Bs[cur ^ 1]);
            dst[tid] = w0;
            dst[tid + 256] = w1;
        }
        __syncthreads();
    }
    #pragma unroll
    for (int m = 0; m < 2; ++m) {
        #pragma unroll
        for (int r = 0; r < 4; ++r) {
            int gr = rowBase + wrow + m * 16 + fg * 4 + r;
            if (gr >= n) continue;
            #pragma unroll
            for (int nn = 0; nn < 2; ++nn) {
                int gc = cb6 * 64 + wcol + nn * 16 + fr;
                float v = acc[m][nn][r] + bias[gc];
                outF[(size_t)gr * 256 + gc] = v;
                dupB[swzA(gr, gc)] = f2bf(v);
            }
        }
    }
}

// ---------- MFMA block-diagonal transform over ALL rels (single K or V phase) ----------
// grid (maxRelRows/128, 8 heads, 8 rels). in = inPb + srcOfs; out = arena + outOfs.
__global__ __launch_bounds__(256) void bd_all(
    const unsigned short* __restrict__ inPb, const float* __restrict__ Rl,
    const float* __restrict__ priL, int isV,
    unsigned short* __restrict__ outAll, BdAllArgs A)
{
    const int rel = blockIdx.z;
    const int n = A.rows[rel];
    const int rowBase = blockIdx.x * 128;
    if (rowBase >= n) return;
    const unsigned short* in = inPb + (size_t)A.srcOfs[rel] * 256;
    const float* R = Rl + (size_t)rel * 8192;
    unsigned short* out = outAll + (size_t)A.outOfs[rel] * 256;
    const int head = blockIdx.y;
    const float oscale = isV ? 1.f : (priL[rel * 8 + head] * 0.17677669529663687f);
    const int tid = threadIdx.x, lane = tid & 63, wv = tid >> 6;
    const int fr = lane & 15, fg = lane >> 4;
    const float* Rh = R + head * 1024;
    bf16x8 b0, b1;
    #pragma unroll
    for (int j = 0; j < 8; ++j) {
        b0[j] = (short)f2bf(Rh[(fg * 8 + j) * 32 + fr] * oscale);
        b1[j] = (short)f2bf(Rh[(fg * 8 + j) * 32 + 16 + fr] * oscale);
    }
    const int r0 = rowBase + wv * 32 + fr;
    const int r1 = r0 + 16;
    const int rc0 = (r0 < n) ? r0 : n - 1;
    const int rc1 = (r1 < n) ? r1 : n - 1;
    bf16x8 a0 = *reinterpret_cast<const bf16x8*>(in + (size_t)rc0 * 256 + head * 32 + fg * 8);
    bf16x8 a1 = *reinterpret_cast<const bf16x8*>(in + (size_t)rc1 * 256 + head * 32 + fg * 8);
    f32x4 acc00 = 0.f, acc01 = 0.f, acc10 = 0.f, acc11 = 0.f;
    acc00 = __builtin_amdgcn_mfma_f32_16x16x32_bf16(a0, b0, acc00, 0, 0, 0);
    acc01 = __builtin_amdgcn_mfma_f32_16x16x32_bf16(a0, b1, acc01, 0, 0, 0);
    acc10 = __builtin_amdgcn_mfma_f32_16x16x32_bf16(a1, b0, acc10, 0, 0, 0);
    acc11 = __builtin_amdgcn_mfma_f32_16x16x32_bf16(a1, b1, acc11, 0, 0, 0);
    const int colB = head * 32 + fr;
    #pragma unroll
    for (int r = 0; r < 4; ++r) {
        int g0 = rowBase + wv * 32 + fg * 4 + r;
        if (g0 < n) {
            out[(size_t)g0 * 256 + colB]      = f2bf(acc00[r]);
            out[(size_t)g0 * 256 + colB + 16] = f2bf(acc01[r]);
        }
        int g1 = g0 + 16;
        if (g1 < n) {
            out[(size_t)g1 * 256 + colB]      = f2bf(acc10[r]);
            out[(size_t)g1 * 256 + colB + 16] = f2bf(acc11[r]);
        }
    }
}

// ---------- EK1 over ALL rels (grid.y = 8) ----------
__global__ __launch_bounds__(256) void ek1_all(
    const unsigned short* __restrict__ qPb, const unsigned short* __restrict__ kattAll,
    float* __restrict__ alog, Ek1AllArgs A)
{
    const int rel = blockIdx.y;
    int gid = blockIdx.x * 256 + threadIdx.x;
    int e = gid >> 3, h = gid & 7;
    if (e >= A.E[rel]) return;
    int s = A.src[rel][e], d = A.dst[rel][e];
    const u16x8* q8 = reinterpret_cast<const u16x8*>(qPb + ((size_t)(A.qOfs[rel] + d)) * 256 + h * 32);
    const u16x8* k8 = reinterpret_cast<const u16x8*>(kattAll + ((size_t)(A.kOfs[rel] + s)) * 256 + h * 32);
    float a = 0.f;
    #pragma unroll
    for (int j = 0; j < 4; ++j) {
        u16x8 qv = q8[j], kv = k8[j];
        #pragma unroll
        for (int m = 0; m < 8; ++m) a += bfd(qv[m]) * bfd(kv[m]);
    }
    alog[(size_t)(A.eBase[rel] + e) * 8 + h] = a;
}

// ---------- EK3 over ALL dst nodes (type lookup), online softmax, swizzled bf16 out ----------
__global__ __launch_bounds__(256) void ek3_all(
    const unsigned short* __restrict__ vmsgAll, const float* __restrict__ alog,
    const int* __restrict__ rowptrAll, const int* __restrict__ eidxAll,
    const float* __restrict__ te7, unsigned short* __restrict__ tB, Ek3AllArgs A)
{
    __shared__ float sTe[224];
    if (threadIdx.x < 224) sTe[threadIdx.x] = te7[threadIdx.x];
    __syncthreads();
    int wv = threadIdx.x >> 6, lane = threadIdx.x & 63;
    int dg = blockIdx.x * 4 + wv;
    if (dg >= A.cumN[3]) return;
    const int ty = (dg >= A.cumN[2]) ? 2 : ((dg >= A.cumN[1]) ? 1 : 0);
    const int d = dg - A.cumN[ty];
    const int bl = lane >> 3, hl = lane & 7;
    const int c = lane * 4, hq = lane >> 3;
    float t0 = 0.f, t1 = 0.f, t2 = 0.f, t3 = 0.f;
    const int nr = A.nrT[ty];
    for (int j = 0; j < nr; ++j) {
        const int rel = A.typeRel[ty * 3 + j];
        int base = A.dstBase[rel] + d;
        int beg = rowptrAll[base], end = rowptrAll[base + 1];
        if (beg == end) continue;
        const int* srcp = A.src[rel];
        const int* timp = A.tim[rel];
        int eB = A.eBase[rel], rO = A.vOfs[rel];
        float m = -INFINITY, den = 0.f;
        float a0 = 0.f, a1 = 0.f, a2 = 0.f, a3 = 0.f;
        for (int p0 = beg; p0 < end; p0 += 8) {
            int p = p0 + bl;
            bool valid = p < end;
            int ge = eidxAll[valid ? p : end - 1];
            int le = ge - eB;
            float a = valid ? alog[(size_t)ge * 8 + hl] : -INFINITY;
            int sS = valid ? srcp[le] : 0;
            int tT = (timp && valid) ? timp[le] : 0;
            float bm = a;
            bm = fmaxf(bm, __shfl_xor(bm, 8));
            bm = fmaxf(bm, __shfl_xor(bm, 16));
            bm = fmaxf(bm, __shfl_xor(bm, 32));
            float bmA = __shfl(bm, hq);
            float mN = fmaxf(m, bmA);
            float sc = __expf(m - mN);
            den *= sc; a0 *= sc; a1 *= sc; a2 *= sc; a3 *= sc;
            m = mN;
            float mL = __shfl(mN, hl * 8);
            float ex = valid ? __expf(a - mL) : 0.f;
            float ds = ex;
            ds += __shfl_xor(ds, 8);
            ds += __shfl_xor(ds, 16);
            ds += __shfl_xor(ds, 32);
            den += __shfl(ds, hq);
            int nb = end - p0; if (nb > 8) nb = 8;
            for (int b = 0; b < nb; ++b) {
                float w = __shfl(ex, b * 8 + hq);
                int sB = __shfl(sS, b * 8);
                ushort4 v = *reinterpret_cast<const ushort4*>(vmsgAll + ((size_t)(rO + sB)) * 256 + c);
                float vx = bfd(v.x), vy = bfd(v.y), vz = bfd(v.z), vw = bfd(v.w);
                if (timp) {
                    int tBt = __shfl(tT, b * 8);
                    const float* tp = &sTe[tBt * 32 + (c & 31)];
                    vx += tp[0]; vy += tp[1]; vz += tp[2]; vw += tp[3];
                }
                a0 += w * vx; a1 += w * vy; a2 += w * vz; a3 += w * vw;
            }
        }
        float inv = 1.f / fmaxf(den, 1e-9f);
        t0 += fmaxf(a0 * inv, 0.f); t1 += fmaxf(a1 * inv, 0.f);
        t2 += fmaxf(a2 * inv, 0.f); t3 += fmaxf(a3 * inv, 0.f);
    }
    float os = A.oScale[ty];
    ushort4 o;
    o.x = f2bf(t0 * os); o.y = f2bf(t1 * os);
    o.z = f2bf(t2 * os); o.w = f2bf(t3 * os);
    *reinterpret_cast<ushort4*>(tB + swzA(A.tOfs[ty] + d, c)) = o;
}

// ---------- fused CSR build ----------
__global__ void count_all(CsrArgs A, int* __restrict__ cnt, int totE) {
    int gid = blockIdx.x * 256 + threadIdx.x;
    if (gid >= totE) return;
    int r = 0;
    while (gid >= A.relOfs[r + 1]) ++r;
    int e = gid - A.relOfs[r];
    atomicAdd(&cnt[A.dstBase[r] + A.dst[r][e]], 1);
}
__global__ __launch_bounds__(1024) void scan1_k(const int* __restrict__ cnt, int* __restrict__ part,
                                                int* __restrict__ bsum, int n) {
    __shared__ int buf[1024];
    int tid = threadIdx.x, gid = blockIdx.x * 1024 + tid;
    int x = (gid < n) ? cnt[gid] : 0;
    buf[tid] = x; __syncthreads();
    for (int off = 1; off < 1024; off <<= 1) {
        int y = (tid >= off) ? buf[tid - off] : 0;
        __syncthreads();
        buf[tid] += y;
        __syncthreads();
    }
    if (gid < n) part[gid] = buf[tid];
    if (tid == 1023) bsum[blockIdx.x] = buf[1023];
}
__global__ __launch_bounds__(256) void scan2_k(int* __restrict__ bsum, int nb) {
    __shared__ int buf[256];
    int tid = threadIdx.x;
    buf[tid] = (tid < nb) ? bsum[tid] : 0;
    __syncthreads();
    for (int off = 1; off < 256; off <<= 1) {
        int y = (tid >= off) ? buf[tid - off] : 0;
        __syncthreads();
        buf[tid] += y;
        __syncthreads();
    }
    if (tid < nb) bsum[tid] = buf[tid];
}
__global__ void scan3_k(const int* __restrict__ cnt, const int* __restrict__ part,
                        const int* __restrict__ bsum, int* __restrict__ rowptr,
                        int* __restrict__ cur, int n) {
    int gid = blockIdx.x * 256 + threadIdx.x;
    if (gid < n) {
        int b = gid >> 10;
        int add = (b > 0) ? bsum[b - 1] : 0;
        int inc = part[gid] + add;
        rowptr[gid + 1] = inc;
        cur[gid] = inc - cnt[gid];
    }
    if (gid == 0) rowptr[0] = 0;
}
__global__ void scatter_all(CsrArgs A, int* __restrict__ cur, int* __restrict__ eidx, int totE) {
    int gid = blockIdx.x * 256 + threadIdx.x;
    if (gid >= totE) return;
    int r = 0;
    while (gid >= A.relOfs[r + 1]) ++r;
    int e = gid - A.relOfs[r];
    int p = atomicAdd(&cur[A.dstBase[r] + A.dst[r][e]], 1);
    eidx[p] = gid;
}

// ---------- merged skip-mix + layernorm over concat rows ----------
__global__ __launch_bounds__(256) void mix_ln_all(
    float* __restrict__ h, unsigned short* __restrict__ hB, const float* __restrict__ trans,
    const float* __restrict__ skipP, const float* __restrict__ g, const float* __restrict__ b,
    MLArgs M)
{
    int row = blockIdx.x;
    int t = (row >= M.rowOfs[2]) ? 2 : ((row >= M.rowOfs[1]) ? 1 : 0);
    int d = row - M.rowOfs[t];
    if (d >= M.nLoc[t]) return;
    int j = M.li3 + t;
    int c = threadIdx.x;
    float alpha = 1.f / (1.f + expf(-skipP[j]));
    size_t off = (size_t)row * 256 + c;
    float o = trans[off] * alpha + h[off] * (1.f - alpha);
    float s = o, ss = o * o;
    #pragma unroll
    for (int dd = 1; dd < 64; dd <<= 1) { s += __shfl_xor(s, dd); ss += __shfl_xor(ss, dd); }
    __shared__ float rS[4], rSS[4];
    int w = threadIdx.x >> 6, lane = threadIdx.x & 63;
    if (lane == 0) { rS[w] = s; rSS[w] = ss; }
    __syncthreads();
    float S = rS[0] + rS[1] + rS[2] + rS[3];
    float SS = rSS[0] + rSS[1] + rSS[2] + rSS[3];
    float mean = S * (1.f / 256.f);
    float var = fmaxf(SS * (1.f / 256.f) - mean * mean, 0.f);
    float rs = rsqrtf(var + 1e-5f);
    float v = (o - mean) * rs * g[(size_t)j * 256 + c] + b[(size_t)j * 256 + c];
    h[off] = v;
    hB[swzA(row, c)] = f2bf(v);
}

// ---------- group max ----------
__global__ __launch_bounds__(256) void gmax_all(GmaxArgs A, unsigned* __restrict__ gi) {
    int ty = blockIdx.y;
    int n = A.n[ty];
    int r0 = blockIdx.x * 64;
    if (r0 >= n) return;
    int col = threadIdx.x;
    const float* hp = A.hp[ty];
    const int* grp = A.grp[ty];
    int cbase = A.colBase[ty];
    int rend = (r0 + 64 < n) ? r0 + 64 : n;
    int cur = grp[r0];
    float m = -INFINITY;
    for (int r = r0; r < rend; ++r) {
        int g = grp[r];
        if (g != cur) {
            atomicMax(&gi[cur * 768 + cbase + col], encf(m));
            cur = g; m = -INFINITY;
        }
        m = fmaxf(m, hp[(size_t)r * 256 + col]);
    }
    atomicMax(&gi[cur * 768 + cbase + col], encf(m));
}

__global__ void gi_init(unsigned* __restrict__ gi) {
    int i = blockIdx.x * 256 + threadIdx.x;
    if (i < 16 * 768) gi[i] = 0x007FFFFFu;
}

// ---------- final ----------
__global__ __launch_bounds__(1024) void final_k(const unsigned* __restrict__ gi,
                                                const float* __restrict__ out_w,
                                                const float* __restrict__ out_b,
                                                const float* __restrict__ y,
                                                float* __restrict__ out) {
    int w = threadIdx.x >> 6, lane = threadIdx.x & 63;
    float s = 0.f;
    for (int c = lane; c < 768; c += 64) s += decf(gi[w * 768 + c]) * out_w[c];
    #pragma unroll
    for (int d = 1; d < 64; d <<= 1) s += __shfl_xor(s, d);
    __shared__ float lloss[16];
    if (lane == 0) {
        float z = s + out_b[0];
        out[1 + w] = 1.f / (1.f + expf(-z));
        lloss[w] = fmaxf(z, 0.f) - z * y[w] + log1pf(expf(-fabsf(z)));
    }
    __syncthreads();
    if (threadIdx.x == 0) {
        float L = 0.f;
        for (int g2 = 0; g2 < 16; ++g2) L += lloss[g2];
        out[0] = L * (1.f / 16.f);
    }
}

extern "C" void kernel_launch(void* const* d_in, const int* in_sizes, int n_in,
                              void* d_out, int out_size, void* d_ws, size_t ws_size,
                              hipStream_t stream) {
    const int* word_id   = (const int*)d_in[0];
    const int* topic_id  = (const int*)d_in[1];
    const int* g_word    = (const int*)d_in[2];
    const int* g_topic   = (const int*)d_in[3];
    const int* g_doc     = (const int*)d_in[4];
    const int* src_ww = (const int*)d_in[5];  const int* dst_ww = (const int*)d_in[6];  const int* time_ww = (const int*)d_in[7];
    const int* src_wd = (const int*)d_in[8];  const int* dst_wd = (const int*)d_in[9];  const int* time_wd = (const int*)d_in[10];
    const int* src_wt = (const int*)d_in[11]; const int* dst_wt = (const int*)d_in[12]; const int* time_wt = (const int*)d_in[13];
    const int* src_td = (const int*)d_in[14]; const int* dst_td = (const int*)d_in[15]; const int* time_td = (const int*)d_in[16];
    const int* src_tt = (const int*)d_in[17]; const int* dst_tt = (const int*)d_in[18];
    const float* y_data      = (const float*)d_in[19];
    const float* word_embeds = (const float*)d_in[20];
    const float* topic_embeds= (const float*)d_in[21];
    const float* doc_gen     = (const float*)d_in[22];
    const float* adapt_w     = (const float*)d_in[23];
    const float* adapt_b     = (const float*)d_in[24];
    const float* time_tab    = (const float*)d_in[25];
    const float* time_w      = (const float*)d_in[26];
    const float* time_b      = (const float*)d_in[27];
    const float* kW = (const float*)d_in[28];
    const float* qW = (const float*)d_in[29];
    const float* vW = (const float*)d_in[30];
    const float* aW = (const float*)d_in[31];
    const float* kB = (const float*)d_in[32];
    const float* qB = (const float*)d_in[33];
    const float* vB = (const float*)d_in[34];
    const float* aB = (const float*)d_in[35];
    const float* skip = (const float*)d_in[36];
    const float* ln_g = (const float*)d_in[37];
    const float* ln_b = (const float*)d_in[38];
    const float* pri  = (const float*)d_in[39];
    const float* attR = (const float*)d_in[40];
    const float* msgR = (const float*)d_in[41];
    const float* out_w = (const float*)d_in[42];
    const float* out_b = (const float*)d_in[43];

    const int NW = in_sizes[0], NT = in_sizes[1], ND = in_sizes[4];
    const int E_ww = in_sizes[5], E_wd = in_sizes[8], E_wt = in_sizes[11],
              E_td = in_sizes[14], E_tt = in_sizes[17];
    const int nN[3] = {NW, NT, ND};
    const float invNin[3] = {1.f / 3.f, 1.f / 3.f, 1.f / 2.f};

    struct Rel { int e, s, d; const int* src; const int* dst; const int* tim; int E; };
    const Rel rels[8] = {
        {0, 0, 1, src_wt, dst_wt, time_wt, E_wt},
        {1, 0, 2, src_wd, dst_wd, time_wd, E_wd},
        {2, 1, 2, src_td, dst_td, time_td, E_td},
        {3, 1, 1, src_tt, dst_tt, nullptr, E_tt},
        {4, 0, 0, src_ww, dst_ww, time_ww, E_ww},
        {5, 1, 0, dst_wt, src_wt, time_wt, E_wt},
        {6, 2, 1, dst_td, src_td, time_td, E_td},
        {7, 2, 0, dst_wd, src_wd, time_wd, E_wd},
    };

    int relOfs[9]; relOfs[0] = 0;
    int dstBase[8]; int acc = 0;
    for (int r = 0; r < 8; ++r) { relOfs[r + 1] = relOfs[r] + rels[r].E; dstBase[r] = acc; acc += nN[rels[r].d]; }
    const int totE = relOfs[8], totD = acc;

    // per-rel rows in the shared katt/vmsg arena
    int relRowOfs[8], relRowsTot = 0, maxRelRows = 0, maxE = 0;
    for (int r = 0; r < 8; ++r) {
        relRowOfs[r] = relRowsTot;
        relRowsTot += nN[rels[r].s];
        if (nN[rels[r].s] > maxRelRows) maxRelRows = nN[rels[r].s];
        if (rels[r].E > maxE) maxE = rels[r].E;
    }

    int nPad[3], rowOfsT[4];
    rowOfsT[0] = 0;
    for (int i = 0; i < 3; ++i) { nPad[i] = (nN[i] + 63) & ~63; rowOfsT[i + 1] = rowOfsT[i] + nPad[i]; }
    const int totPad = rowOfsT[3];

    float* base = (float*)d_ws;
    size_t off = 0;
    auto take = [&](size_t nElems) { float* p = base + off; off += (nElems + 63) & ~(size_t)63; return p; };
    float* hPbase = take((size_t)totPad * 256);
    unsigned short* hB = (unsigned short*)take((size_t)totPad * 128);
    unsigned short* tB = (unsigned short*)take((size_t)totPad * 128);
    unsigned short* kPb = (unsigned short*)take((size_t)totPad * 128);
    unsigned short* qPb = (unsigned short*)take((size_t)totPad * 128);
    unsigned short* vPb = (unsigned short*)take((size_t)totPad * 128);
    // single arena: katt (phase 1) then vmsg (phase 2); trans (f32) aliases after edge phase
    size_t arenaFloats = (size_t)relRowsTot * 128;   // rows * 256 bf16 = rows*128 floats
    if ((size_t)totPad * 256 > arenaFloats) arenaFloats = (size_t)totPad * 256;
    float* uni = take(arenaFloats);
    unsigned short* arena = (unsigned short*)uni;
    float* trans = uni;
    unsigned short* WT = (unsigned short*)take((size_t)25 * 32768);
    float* alog = take((size_t)totE * 8);
    float* te7  = take(7 * 32);
    unsigned* gi = (unsigned*)take(16 * 768);
    int* cntAll = (int*)take(totD);
    int* part   = (int*)take(totD);
    int* bsum   = (int*)take(256);
    int* rowptrAll = (int*)take(totD + 1);
    int* curAll = (int*)take(totD);
    int* eidxAll = (int*)take(totE);
    (void)ws_size; (void)n_in; (void)out_size;

    te_kernel<<<1, 256, 0, stream>>>(time_tab, time_w, time_b, te7);
    {
        dim3 g(8, 8, 25);
        wtr_kernel<<<g, 256, 0, stream>>>(adapt_w, kW, qW, vW, aW, WT);
    }
    CsrArgs ca;
    for (int r = 0; r < 8; ++r) { ca.dst[r] = rels[r].dst; ca.dstBase[r] = dstBase[r]; }
    for (int r = 0; r < 9; ++r) ca.relOfs[r] = relOfs[r];
    hipMemsetAsync(cntAll, 0, (size_t)totD * sizeof(int), stream);
    count_all<<<(totE + 255) / 256, 256, 0, stream>>>(ca, cntAll, totE);
    int nb = (totD + 1023) / 1024;
    scan1_k<<<nb, 1024, 0, stream>>>(cntAll, part, bsum, totD);
    scan2_k<<<1, 256, 0, stream>>>(bsum, nb);
    scan3_k<<<(totD + 255) / 256, 256, 0, stream>>>(cntAll, part, bsum, rowptrAll, curAll, totD);
    scatter_all<<<(totE + 255) / 256, 256, 0, stream>>>(ca, curAll, eidxAll, totE);
    gi_init<<<48, 256, 0, stream>>>(gi);

    {
        dim3 g((NW + 63) / 64, 4);
        gemm_init<<<g, 256, 0, stream>>>(word_embeds, word_id, WT, adapt_b, hPbase, hB, NW);
    }
    gather_rows<<<NT, 256, 0, stream>>>(topic_embeds, topic_id,
                                        hPbase + (size_t)rowOfsT[1] * 256,
                                        hB + (size_t)rowOfsT[1] * 256, NT);
    bcast_row<<<ND, 256, 0, stream>>>(doc_gen,
                                      hPbase + (size_t)rowOfsT[2] * 256,
                                      hB + (size_t)rowOfsT[2] * 256, ND);

    // ---- flattened arg structs ----
    BdAllArgs ba;
    Ek1AllArgs e1;
    Ek3AllArgs e3;
    for (int r = 0; r < 8; ++r) {
        const Rel& R = rels[r];
        ba.rows[r] = nN[R.s];
        ba.srcOfs[r] = rowOfsT[R.s];
        ba.outOfs[r] = relRowOfs[r];
        e1.src[r] = R.src; e1.dst[r] = R.dst; e1.E[r] = R.E; e1.eBase[r] = relOfs[r];
        e1.kOfs[r] = relRowOfs[r]; e1.qOfs[r] = rowOfsT[R.d];
        e3.src[r] = R.src; e3.tim[r] = R.tim; e3.eBase[r] = relOfs[r];
        e3.dstBase[r] = dstBase[r]; e3.vOfs[r] = relRowOfs[r];
    }
    const int typeRel[9] = {4, 5, 7, 0, 3, 6, 1, 2, 0};
    for (int i = 0; i < 9; ++i) e3.typeRel[i] = typeRel[i];
    e3.nrT[0] = 3; e3.nrT[1] = 3; e3.nrT[2] = 2;
    e3.cumN[0] = 0; e3.cumN[1] = NW; e3.cumN[2] = NW + NT; e3.cumN[3] = NW + NT + ND;
    for (int i = 0; i < 3; ++i) { e3.tOfs[i] = rowOfsT[i]; e3.oScale[i] = invNin[i]; }

    GBArgs gb;
    for (int i = 0; i < 4; ++i) gb.rb[i] = rowOfsT[i] / 64;
    for (int i = 0; i < 3; ++i) gb.nLoc[i] = nN[i];
    MLArgs ml;
    for (int i = 0; i < 4; ++i) ml.rowOfs[i] = rowOfsT[i];
    for (int i = 0; i < 3; ++i) ml.nLoc[i] = nN[i];

    const int totBlocks = totPad / 64;
    const int totD3 = NW + NT + ND;
    for (int li = 0; li < LNUM; ++li) {
        gb.li3 = li * 3; ml.li3 = li * 3;
        {
            dim3 g(totBlocks, 4);
            gemm_batch<<<g, 256, 0, stream>>>(hB, WT, 1, 3, kB, qB, vB,
                                              kPb, qPb, vPb, 1, gb);
        }
        {
            dim3 g((maxRelRows + 127) / 128, 8, 8);
            bd_all<<<g, 256, 0, stream>>>(kPb, attR + (size_t)li * 8 * 8192,
                                          pri + (size_t)li * 8 * 8, 0, arena, ba);
        }
        {
            dim3 g((maxE * 8 + 255) / 256, 8);
            ek1_all<<<g, 256, 0, stream>>>(qPb, arena, alog, e1);
        }
        {
            dim3 g((maxRelRows + 127) / 128, 8, 8);
            bd_all<<<g, 256, 0, stream>>>(vPb, msgR + (size_t)li * 8 * 8192,
                                          pri + (size_t)li * 8 * 8, 1, arena, ba);
        }
        ek3_all<<<(totD3 + 3) / 4, 256, 0, stream>>>(arena, alog, rowptrAll, eidxAll,
                                                     te7, tB, e3);
        {
            dim3 g(totBlocks, 4);
            gemm_batch<<<g, 256, 0, stream>>>(tB, WT, 19, 1, aB, aB, aB,
                                              trans, trans, trans, 0, gb);
        }
        mix_ln_all<<<totPad, 256, 0, stream>>>(hPbase, hB, trans, skip, ln_g, ln_b, ml);
    }

    GmaxArgs ga;
    ga.hp[0] = hPbase + (size_t)rowOfsT[2] * 256; ga.grp[0] = g_doc;   ga.n[0] = ND; ga.colBase[0] = 0;
    ga.hp[1] = hPbase;                             ga.grp[1] = g_word;  ga.n[1] = NW; ga.colBase[1] = 256;
    ga.hp[2] = hPbase + (size_t)rowOfsT[1] * 256; ga.grp[2] = g_topic; ga.n[2] = NT; ga.colBase[2] = 512;
    int maxN = NW > ND ? (NW > NT ? NW : NT) : (ND > NT ? ND : NT);
    dim3 gg((maxN + 63) / 64, 3);
    gmax_all<<<gg, 256, 0, stream>>>(ga, gi);
    final_k<<<1, 1024, 0, stream>>>(gi, out_w, out_b, y_data, (float*)d_out);
}

// Round 17
// 658.143 us; speedup vs baseline: 1.1235x; 1.0277x over previous
//
#include <hip/hip_runtime.h>
#include <hip/hip_bf16.h>
#include <math.h>

#define H 8
#define DK 32
#define NHID 256
#define LNUM 2
#define GNUM 16

typedef float f32x4 __attribute__((ext_vector_type(4)));
typedef short bf16x8 __attribute__((ext_vector_type(8)));
typedef unsigned short u16x8 __attribute__((ext_vector_type(8)));

__device__ __forceinline__ unsigned encf(float f) {
    unsigned u = __float_as_uint(f);
    return (u & 0x80000000u) ? ~u : (u | 0x80000000u);
}
__device__ __forceinline__ float decf(unsigned u) {
    return __uint_as_float((u & 0x80000000u) ? (u ^ 0x80000000u) : ~u);
}
__device__ __forceinline__ float bfd(unsigned short u) {
    return __uint_as_float(((unsigned)u) << 16);
}
__device__ __forceinline__ unsigned short f2bf(float x) {
    __hip_bfloat16 b = __float2bfloat16(x);
    return *reinterpret_cast<unsigned short*>(&b);
}

// Panel swizzle: 64-row panels, LDS-image layout. kb = byte offset in 512B row.
#define APAN2(row, kb) ((((kb) >> 7) << 12) + ((row) << 6) + ((((kb) & 127) ^ (((row) & 7) << 4)) >> 1))
__device__ __forceinline__ size_t swzA(int row, int col /*elem*/) {
    return (((size_t)(row >> 6)) << 14) + (size_t)APAN2(row & 63, col * 2);
}
#define SWZB(row, kb)  (((row) << 6) + ((((kb) ^ (((row) & 7) << 4))) >> 1))

// ---------- by-value arg structs ----------
struct CsrArgs  { const int* dst[8]; const int* srcA[8]; const int* timA[8];
                  int relOfs[9]; int dstBase[8]; };
struct BdAllArgs{ int rows[8]; int srcOfs[8]; int outOfs[8]; };
struct Ek1PosArgs{ int kOfs[8]; int qOfs[8]; };
struct Ek3AllArgs{ int dstBase[8]; int vOfs[8]; int hasTim[8]; int typeRel[9]; int nrT[3];
                   int cumN[4]; int tOfs[3]; float oScale[3]; };
struct GmaxArgs { const float* hp[3]; const int* grp[3]; int n[3]; int colBase[3]; };
struct GBArgs   { int rb[4]; int nLoc[3]; int li3; };
struct MLArgs   { int rowOfs[4]; int nLoc[3]; int li3; };

// ---------- temporal encoding table ----------
__global__ void te_kernel(const float* __restrict__ time_tab, const float* __restrict__ time_w,
                          const float* __restrict__ time_b, float* __restrict__ te7) {
    int t = threadIdx.x >> 5, j = threadIdx.x & 31;
    if (t < 7) {
        float s = time_b[j];
        #pragma unroll
        for (int i = 0; i < 32; ++i) s += time_tab[t * 32 + i] * time_w[i * 32 + j];
        te7[t * 32 + j] = s;
    }
}

__global__ void gather_rows(const float* __restrict__ emb, const int* __restrict__ idx,
                            float* __restrict__ out, unsigned short* __restrict__ outB, int n) {
    int row = blockIdx.x, c = threadIdx.x;
    if (row < n) {
        float v = emb[(size_t)idx[row] * 256 + c];
        out[(size_t)row * 256 + c] = v;
        outB[swzA(row, c)] = f2bf(v);
    }
}

__global__ void bcast_row(const float* __restrict__ src, float* __restrict__ out,
                          unsigned short* __restrict__ outB, int n) {
    int row = blockIdx.x, c = threadIdx.x;
    if (row < n) {
        float v = src[c];
        out[(size_t)row * 256 + c] = v;
        outB[swzA(row, c)] = f2bf(v);
    }
}

// ---------- weight transpose+bf16: tile-linear pre-swizzled chunks ----------
__global__ __launch_bounds__(256) void wtr_kernel(
    const float* __restrict__ adaptW, const float* __restrict__ kW, const float* __restrict__ qW,
    const float* __restrict__ vW, const float* __restrict__ aW, unsigned short* __restrict__ WT) {
    int z = blockIdx.z;
    const float* src;
    if (z == 0) src = adaptW;
    else if (z < 7)  src = kW + (size_t)(z - 1) * 65536;
    else if (z < 13) src = qW + (size_t)(z - 7) * 65536;
    else if (z < 19) src = vW + (size_t)(z - 13) * 65536;
    else             src = aW + (size_t)(z - 19) * 65536;
    unsigned short* dst = WT + (size_t)z * 65536;
    __shared__ float tile[32][33];
    int tx = threadIdx.x & 31, ty = threadIdx.x >> 5;
    int kb = blockIdx.x * 32, cb = blockIdx.y * 32;
    #pragma unroll
    for (int i = 0; i < 4; ++i)
        tile[ty + i * 8][tx] = src[(size_t)(kb + ty + i * 8) * 256 + cb + tx];
    __syncthreads();
    #pragma unroll
    for (int i = 0; i < 4; ++i) {
        int col = cb + ty + i * 8, k = kb + tx;
        dst[((col >> 6) * 4 + (k >> 6)) * 4096 + SWZB(col & 63, (k & 63) * 2)] =
            f2bf(tile[tx][ty + i * 8]);
    }
}

// ---------- batched MFMA GEMM over concat rows, 64-col blocks, chunk-linear B dbuf ----------
__global__ __launch_bounds__(256) void gemm_batch(
    const unsigned short* __restrict__ Apan,
    const unsigned short* __restrict__ WT, int wBase, int nz,
    const float* __restrict__ b0, const float* __restrict__ b1, const float* __restrict__ b2,
    void* __restrict__ o0, void* __restrict__ o1, void* __restrict__ o2,
    int outBf16, GBArgs ga)
{
    __shared__ unsigned short As[64 * 256];
    __shared__ unsigned short Bs[2][4096];
    const int tid = threadIdx.x;
    const int lane = tid & 63, wv = tid >> 6;
    const int b = blockIdx.x;
    const int t = (b >= ga.rb[2]) ? 2 : ((b >= ga.rb[1]) ? 1 : 0);
    const int nLoc = ga.nLoc[t];
    const int locRowBase = (b - ga.rb[t]) * 64;
    const int cb6 = blockIdx.y;
    const int mBase = wBase + ga.li3 + t;
    {
        const u16x8* src = reinterpret_cast<const u16x8*>(Apan + (((size_t)b) << 14));
        u16x8* dst = reinterpret_cast<u16x8*>(As);
        #pragma unroll
        for (int it = 0; it < 8; ++it)
            dst[it * 256 + tid] = src[it * 256 + tid];
    }
    const int fr = lane & 15, fg = lane >> 4;
    const int wrow = (wv & 1) * 32, wcol = (wv >> 1) * 32;
    const int nt = nz * 4;
    {
        const u16x8* src = reinterpret_cast<const u16x8*>(WT + (size_t)mBase * 65536 + (size_t)(cb6 * 4 + 0) * 4096);
        u16x8* dst = reinterpret_cast<u16x8*>(Bs[0]);
        dst[tid] = src[tid];
        dst[tid + 256] = src[tid + 256];
    }
    __syncthreads();

    f32x4 acc[2][2];
    #pragma unroll
    for (int m = 0; m < 2; ++m)
        #pragma unroll
        for (int nn = 0; nn < 2; ++nn) acc[m][nn] = 0.f;

    for (int tt2 = 0; tt2 < nt; ++tt2) {
        const int cur = tt2 & 1;
        const int ks = tt2 & 3, z = tt2 >> 2;
        u16x8 w0, w1;
        const bool pf = (tt2 + 1 < nt);
        if (pf) {
            int tn = tt2 + 1;
            const u16x8* src = reinterpret_cast<const u16x8*>(
                WT + (size_t)(mBase + (tn >> 2) * 6) * 65536 + (size_t)(cb6 * 4 + (tn & 3)) * 4096);
            w0 = src[tid];
            w1 = src[tid + 256];
        }
        #pragma unroll
        for (int kk = 0; kk < 2; ++kk) {
            bf16x8 af0 = *reinterpret_cast<bf16x8*>(&As[APAN2(wrow + fr,      ks * 128 + kk * 64 + fg * 16)]);
            bf16x8 af1 = *reinterpret_cast<bf16x8*>(&As[APAN2(wrow + 16 + fr, ks * 128 + kk * 64 + fg * 16)]);
            bf16x8 bf0 = *reinterpret_cast<bf16x8*>(&Bs[cur][SWZB(wcol + fr,      kk * 64 + fg * 16)]);
            bf16x8 bf1 = *reinterpret_cast<bf16x8*>(&Bs[cur][SWZB(wcol + 16 + fr, kk * 64 + fg * 16)]);
            acc[0][0] = __builtin_amdgcn_mfma_f32_16x16x32_bf16(af0, bf0, acc[0][0], 0, 0, 0);
            acc[0][1] = __builtin_amdgcn_mfma_f32_16x16x32_bf16(af0, bf1, acc[0][1], 0, 0, 0);
            acc[1][0] = __builtin_amdgcn_mfma_f32_16x16x32_bf16(af1, bf0, acc[1][0], 0, 0, 0);
            acc[1][1] = __builtin_amdgcn_mfma_f32_16x16x32_bf16(af1, bf1, acc[1][1], 0, 0, 0);
        }
        if (pf) {
            u16x8* dst = reinterpret_cast<u16x8*>(Bs[cur ^ 1]);
            dst[tid] = w0;
            dst[tid + 256] = w1;
        }
        if (ks == 3) {
            const float* biasB = (z == 0) ? b0 : ((z == 1) ? b1 : b2);
            const float* bias = biasB + (size_t)(ga.li3 + t) * 256;
            void* outp = (z == 0) ? o0 : ((z == 1) ? o1 : o2);
            #pragma unroll
            for (int m = 0; m < 2; ++m) {
                #pragma unroll
                for (int r = 0; r < 4; ++r) {
                    int lr = locRowBase + wrow + m * 16 + fg * 4 + r;
                    if (lr >= nLoc) continue;
                    size_t gr = (size_t)b * 64 + wrow + m * 16 + fg * 4 + r;
                    #pragma unroll
                    for (int nn = 0; nn < 2; ++nn) {
                        int gc = cb6 * 64 + wcol + nn * 16 + fr;
                        float v = acc[m][nn][r] + bias[gc];
                        if (outBf16) ((unsigned short*)outp)[gr * 256 + gc] = f2bf(v);
                        else         ((float*)outp)[gr * 256 + gc] = v;
                    }
                }
            }
            #pragma unroll
            for (int m = 0; m < 2; ++m)
                #pragma unroll
                for (int nn = 0; nn < 2; ++nn) acc[m][nn] = 0.f;
        }
        __syncthreads();
    }
}

// ---------- init GEMM (word adapt) ----------
__global__ __launch_bounds__(256) void gemm_init(
    const float* __restrict__ A, const int* __restrict__ gidx,
    const unsigned short* __restrict__ WT, const float* __restrict__ bias,
    float* __restrict__ outF, unsigned short* __restrict__ dupB, int n)
{
    __shared__ unsigned short As[64 * 256];
    __shared__ unsigned short Bs[2][4096];
    const int tid = threadIdx.x;
    const int lane = tid & 63, wv = tid >> 6;
    const int rowBase = blockIdx.x * 64;
    const int cb6 = blockIdx.y;
    #pragma unroll 4
    for (int it = 0; it < 16; ++it) {
        int row = it * 4 + wv;
        int r = rowBase + row;
        ushort4 p = make_ushort4(0, 0, 0, 0);
        if (r < n) {
            int ar = gidx[r];
            float4 v = *reinterpret_cast<const float4*>(A + (size_t)ar * 256 + lane * 4);
            p.x = f2bf(v.x); p.y = f2bf(v.y); p.z = f2bf(v.z); p.w = f2bf(v.w);
        }
        *reinterpret_cast<ushort4*>(&As[APAN2(row, lane * 8)]) = p;
    }
    const int fr = lane & 15, fg = lane >> 4;
    const int wrow = (wv & 1) * 32, wcol = (wv >> 1) * 32;
    {
        const u16x8* src = reinterpret_cast<const u16x8*>(WT + (size_t)(cb6 * 4 + 0) * 4096);
        u16x8* dst = reinterpret_cast<u16x8*>(Bs[0]);
        dst[tid] = src[tid];
        dst[tid + 256] = src[tid + 256];
    }
    __syncthreads();
    f32x4 acc[2][2];
    #pragma unroll
    for (int m = 0; m < 2; ++m)
        #pragma unroll
        for (int nn = 0; nn < 2; ++nn) acc[m][nn] = 0.f;
    for (int t = 0; t < 4; ++t) {
        const int cur = t & 1;
        u16x8 w0, w1;
        const bool pf = (t + 1 < 4);
        if (pf) {
            const u16x8* src = reinterpret_cast<const u16x8*>(WT + (size_t)(cb6 * 4 + t + 1) * 4096);
            w0 = src[tid];
            w1 = src[tid + 256];
        }
        #pragma unroll
        for (int kk = 0; kk < 2; ++kk) {
            bf16x8 af0 = *reinterpret_cast<bf16x8*>(&As[APAN2(wrow + fr,      t * 128 + kk * 64 + fg * 16)]);
            bf16x8 af1 = *reinterpret_cast<bf16x8*>(&As[APAN2(wrow + 16 + fr, t * 128 + kk * 64 + fg * 16)]);
            bf16x8 bf0 = *reinterpret_cast<bf16x8*>(&Bs[cur][SWZB(wcol + fr,      kk * 64 + fg * 16)]);
            bf16x8 bf1 = *reinterpret_cast<bf16x8*>(&Bs[cur][SWZB(wcol + 16 + fr, kk * 64 + fg * 16)]);
            acc[0][0] = __builtin_amdgcn_mfma_f32_16x16x32_bf16(af0, bf0, acc[0][0], 0, 0, 0);
            acc[0][1] = __builtin_amdgcn_mfma_f32_16x16x32_bf16(af0, bf1, acc[0][1], 0, 0, 0);
            acc[1][0] = __builtin_amdgcn_mfma_f32_16x16x32_bf16(af1, bf0, acc[1][0], 0, 0, 0);
            acc[1][1] = __builtin_amdgcn_mfma_f32_16x16x32_bf16(af1, bf1, acc[1][1], 0, 0, 0);
        }
        if (pf) {
            u16x8* dst = reinterpret_cast<u16x8*>(Bs[cur ^ 1]);
            dst[tid] = w0;
            dst[tid + 256] = w1;
        }
        __syncthreads();
    }
    #pragma unroll
    for (int m = 0; m < 2; ++m) {
        #pragma unroll
        for (int r = 0; r < 4; ++r) {
            int gr = rowBase + wrow + m * 16 + fg * 4 + r;
            if (gr >= n) continue;
            #pragma unroll
            for (int nn = 0; nn < 2; ++nn) {
                int gc = cb6 * 64 + wcol + nn * 16 + fr;
                float v = acc[m][nn][r] + bias[gc];
                outF[(size_t)gr * 256 + gc] = v;
                dupB[swzA(gr, gc)] = f2bf(v);
            }
        }
    }
}

// ---------- MFMA block-diagonal transform over ALL rels (single K or V phase) ----------
__global__ __launch_bounds__(256) void bd_all(
    const unsigned short* __restrict__ inPb, const float* __restrict__ Rl,
    const float* __restrict__ priL, int isV,
    unsigned short* __restrict__ outAll, BdAllArgs A)
{
    const int rel = blockIdx.z;
    const int n = A.rows[rel];
    const int rowBase = blockIdx.x * 128;
    if (rowBase >= n) return;
    const unsigned short* in = inPb + (size_t)A.srcOfs[rel] * 256;
    const float* R = Rl + (size_t)rel * 8192;
    unsigned short* out = outAll + (size_t)A.outOfs[rel] * 256;
    const int head = blockIdx.y;
    const float oscale = isV ? 1.f : (priL[rel * 8 + head] * 0.17677669529663687f);
    const int tid = threadIdx.x, lane = tid & 63, wv = tid >> 6;
    const int fr = lane & 15, fg = lane >> 4;
    const float* Rh = R + head * 1024;
    bf16x8 b0, b1;
    #pragma unroll
    for (int j = 0; j < 8; ++j) {
        b0[j] = (short)f2bf(Rh[(fg * 8 + j) * 32 + fr] * oscale);
        b1[j] = (short)f2bf(Rh[(fg * 8 + j) * 32 + 16 + fr] * oscale);
    }
    const int r0 = rowBase + wv * 32 + fr;
    const int r1 = r0 + 16;
    const int rc0 = (r0 < n) ? r0 : n - 1;
    const int rc1 = (r1 < n) ? r1 : n - 1;
    bf16x8 a0 = *reinterpret_cast<const bf16x8*>(in + (size_t)rc0 * 256 + head * 32 + fg * 8);
    bf16x8 a1 = *reinterpret_cast<const bf16x8*>(in + (size_t)rc1 * 256 + head * 32 + fg * 8);
    f32x4 acc00 = 0.f, acc01 = 0.f, acc10 = 0.f, acc11 = 0.f;
    acc00 = __builtin_amdgcn_mfma_f32_16x16x32_bf16(a0, b0, acc00, 0, 0, 0);
    acc01 = __builtin_amdgcn_mfma_f32_16x16x32_bf16(a0, b1, acc01, 0, 0, 0);
    acc10 = __builtin_amdgcn_mfma_f32_16x16x32_bf16(a1, b0, acc10, 0, 0, 0);
    acc11 = __builtin_amdgcn_mfma_f32_16x16x32_bf16(a1, b1, acc11, 0, 0, 0);
    const int colB = head * 32 + fr;
    #pragma unroll
    for (int r = 0; r < 4; ++r) {
        int g0 = rowBase + wv * 32 + fg * 4 + r;
        if (g0 < n) {
            out[(size_t)g0 * 256 + colB]      = f2bf(acc00[r]);
            out[(size_t)g0 * 256 + colB + 16] = f2bf(acc01[r]);
        }
        int g1 = g0 + 16;
        if (g1 < n) {
            out[(size_t)g1 * 256 + colB]      = f2bf(acc10[r]);
            out[(size_t)g1 * 256 + colB + 16] = f2bf(acc11[r]);
        }
    }
}

// ---------- EK1 position-parallel: logits in CSR order ----------
__global__ __launch_bounds__(256) void ek1_pos(
    const unsigned short* __restrict__ qPb, const unsigned short* __restrict__ kattAll,
    const int* __restrict__ payload, const int* __restrict__ drel,
    float* __restrict__ alogC, Ek1PosArgs A, int totE)
{
    int gid = blockIdx.x * 256 + threadIdx.x;
    int p = gid >> 3, h = gid & 7;
    if (p >= totE) return;
    int dr = drel[p];
    int d = dr & 0xFFFFF, rel = dr >> 20;
    int s = payload[p] & 0xFFFF;
    const u16x8* q8 = reinterpret_cast<const u16x8*>(qPb + ((size_t)(A.qOfs[rel] + d)) * 256 + h * 32);
    const u16x8* k8 = reinterpret_cast<const u16x8*>(kattAll + ((size_t)(A.kOfs[rel] + s)) * 256 + h * 32);
    float a = 0.f;
    #pragma unroll
    for (int j = 0; j < 4; ++j) {
        u16x8 qv = q8[j], kv = k8[j];
        #pragma unroll
        for (int m = 0; m < 8; ++m) a += bfd(qv[m]) * bfd(kv[m]);
    }
    alogC[(size_t)p * 8 + h] = a;
}

// ---------- EK3 over ALL dst nodes: coalesced CSR payload, online softmax ----------
__global__ __launch_bounds__(256) void ek3_all(
    const unsigned short* __restrict__ vmsgAll, const float* __restrict__ alogC,
    const int* __restrict__ rowptrAll, const int* __restrict__ payload,
    const float* __restrict__ te7, unsigned short* __restrict__ tB, Ek3AllArgs A)
{
    __shared__ float sTe[224];
    if (threadIdx.x < 224) sTe[threadIdx.x] = te7[threadIdx.x];
    __syncthreads();
    int wv = threadIdx.x >> 6, lane = threadIdx.x & 63;
    int dg = blockIdx.x * 4 + wv;
    if (dg >= A.cumN[3]) return;
    const int ty = (dg >= A.cumN[2]) ? 2 : ((dg >= A.cumN[1]) ? 1 : 0);
    const int d = dg - A.cumN[ty];
    const int bl = lane >> 3, hl = lane & 7;
    const int c = lane * 4, hq = lane >> 3;
    float t0 = 0.f, t1 = 0.f, t2 = 0.f, t3 = 0.f;
    const int nr = A.nrT[ty];
    for (int j = 0; j < nr; ++j) {
        const int rel = A.typeRel[ty * 3 + j];
        int base = A.dstBase[rel] + d;
        int beg = rowptrAll[base], end = rowptrAll[base + 1];
        if (beg == end) continue;
        const int useTim = A.hasTim[rel];
        int rO = A.vOfs[rel];
        float m = -INFINITY, den = 0.f;
        float a0 = 0.f, a1 = 0.f, a2 = 0.f, a3 = 0.f;
        for (int p0 = beg; p0 < end; p0 += 8) {
            int p = p0 + bl;
            bool valid = p < end;
            int pc = valid ? p : end - 1;
            float a = valid ? alogC[(size_t)pc * 8 + hl] : -INFINITY;
            int pk = payload[pc];
            int sS = pk & 0xFFFF, tT = pk >> 16;
            float bm = a;
            bm = fmaxf(bm, __shfl_xor(bm, 8));
            bm = fmaxf(bm, __shfl_xor(bm, 16));
            bm = fmaxf(bm, __shfl_xor(bm, 32));
            float bmA = __shfl(bm, hq);
            float mN = fmaxf(m, bmA);
            float sc = __expf(m - mN);
            den *= sc; a0 *= sc; a1 *= sc; a2 *= sc; a3 *= sc;
            m = mN;
            float mL = __shfl(mN, hl * 8);
            float ex = valid ? __expf(a - mL) : 0.f;
            float ds = ex;
            ds += __shfl_xor(ds, 8);
            ds += __shfl_xor(ds, 16);
            ds += __shfl_xor(ds, 32);
            den += __shfl(ds, hq);
            int nb = end - p0; if (nb > 8) nb = 8;
            for (int b = 0; b < nb; ++b) {
                float w = __shfl(ex, b * 8 + hq);
                int sB = __shfl(sS, b * 8);
                ushort4 v = *reinterpret_cast<const ushort4*>(vmsgAll + ((size_t)(rO + sB)) * 256 + c);
                float vx = bfd(v.x), vy = bfd(v.y), vz = bfd(v.z), vw = bfd(v.w);
                if (useTim) {
                    int tBt = __shfl(tT, b * 8);
                    const float* tp = &sTe[tBt * 32 + (c & 31)];
                    vx += tp[0]; vy += tp[1]; vz += tp[2]; vw += tp[3];
                }
                a0 += w * vx; a1 += w * vy; a2 += w * vz; a3 += w * vw;
            }
        }
        float inv = 1.f / fmaxf(den, 1e-9f);
        t0 += fmaxf(a0 * inv, 0.f); t1 += fmaxf(a1 * inv, 0.f);
        t2 += fmaxf(a2 * inv, 0.f); t3 += fmaxf(a3 * inv, 0.f);
    }
    float os = A.oScale[ty];
    ushort4 o;
    o.x = f2bf(t0 * os); o.y = f2bf(t1 * os);
    o.z = f2bf(t2 * os); o.w = f2bf(t3 * os);
    *reinterpret_cast<ushort4*>(tB + swzA(A.tOfs[ty] + d, c)) = o;
}

// ---------- fused CSR build ----------
__global__ void count_all(CsrArgs A, int* __restrict__ cnt, int totE) {
    int gid = blockIdx.x * 256 + threadIdx.x;
    if (gid >= totE) return;
    int r = 0;
    while (gid >= A.relOfs[r + 1]) ++r;
    int e = gid - A.relOfs[r];
    atomicAdd(&cnt[A.dstBase[r] + A.dst[r][e]], 1);
}
__global__ __launch_bounds__(1024) void scan1_k(const int* __restrict__ cnt, int* __restrict__ part,
                                                int* __restrict__ bsum, int n) {
    __shared__ int buf[1024];
    int tid = threadIdx.x, gid = blockIdx.x * 1024 + tid;
    int x = (gid < n) ? cnt[gid] : 0;
    buf[tid] = x; __syncthreads();
    for (int off = 1; off < 1024; off <<= 1) {
        int y = (tid >= off) ? buf[tid - off] : 0;
        __syncthreads();
        buf[tid] += y;
        __syncthreads();
    }
    if (gid < n) part[gid] = buf[tid];
    if (tid == 1023) bsum[blockIdx.x] = buf[1023];
}
__global__ __launch_bounds__(256) void scan2_k(int* __restrict__ bsum, int nb) {
    __shared__ int buf[256];
    int tid = threadIdx.x;
    buf[tid] = (tid < nb) ? bsum[tid] : 0;
    __syncthreads();
    for (int off = 1; off < 256; off <<= 1) {
        int y = (tid >= off) ? buf[tid - off] : 0;
        __syncthreads();
        buf[tid] += y;
        __syncthreads();
    }
    if (tid < nb) bsum[tid] = buf[tid];
}
__global__ void scan3_k(const int* __restrict__ cnt, const int* __restrict__ part,
                        const int* __restrict__ bsum, int* __restrict__ rowptr,
                        int* __restrict__ cur, int n) {
    int gid = blockIdx.x * 256 + threadIdx.x;
    if (gid < n) {
        int b = gid >> 10;
        int add = (b > 0) ? bsum[b - 1] : 0;
        int inc = part[gid] + add;
        rowptr[gid + 1] = inc;
        cur[gid] = inc - cnt[gid];
    }
    if (gid == 0) rowptr[0] = 0;
}
__global__ void scatter_all(CsrArgs A, int* __restrict__ cur,
                            int* __restrict__ payload, int* __restrict__ drel, int totE) {
    int gid = blockIdx.x * 256 + threadIdx.x;
    if (gid >= totE) return;
    int r = 0;
    while (gid >= A.relOfs[r + 1]) ++r;
    int e = gid - A.relOfs[r];
    int d = A.dst[r][e];
    int p = atomicAdd(&cur[A.dstBase[r] + d], 1);
    int s = A.srcA[r][e];
    int t = A.timA[r] ? A.timA[r][e] : 0;
    payload[p] = s | (t << 16);
    drel[p] = d | (r << 20);
}

// ---------- merged skip-mix + layernorm over concat rows ----------
__global__ __launch_bounds__(256) void mix_ln_all(
    float* __restrict__ h, unsigned short* __restrict__ hB, const float* __restrict__ trans,
    const float* __restrict__ skipP, const float* __restrict__ g, const float* __restrict__ b,
    MLArgs M)
{
    int row = blockIdx.x;
    int t = (row >= M.rowOfs[2]) ? 2 : ((row >= M.rowOfs[1]) ? 1 : 0);
    int d = row - M.rowOfs[t];
    if (d >= M.nLoc[t]) return;
    int j = M.li3 + t;
    int c = threadIdx.x;
    float alpha = 1.f / (1.f + expf(-skipP[j]));
    size_t off = (size_t)row * 256 + c;
    float o = trans[off] * alpha + h[off] * (1.f - alpha);
    float s = o, ss = o * o;
    #pragma unroll
    for (int dd = 1; dd < 64; dd <<= 1) { s += __shfl_xor(s, dd); ss += __shfl_xor(ss, dd); }
    __shared__ float rS[4], rSS[4];
    int w = threadIdx.x >> 6, lane = threadIdx.x & 63;
    if (lane == 0) { rS[w] = s; rSS[w] = ss; }
    __syncthreads();
    float S = rS[0] + rS[1] + rS[2] + rS[3];
    float SS = rSS[0] + rSS[1] + rSS[2] + rSS[3];
    float mean = S * (1.f / 256.f);
    float var = fmaxf(SS * (1.f / 256.f) - mean * mean, 0.f);
    float rs = rsqrtf(var + 1e-5f);
    float v = (o - mean) * rs * g[(size_t)j * 256 + c] + b[(size_t)j * 256 + c];
    h[off] = v;
    hB[swzA(row, c)] = f2bf(v);
}

// ---------- group max ----------
__global__ __launch_bounds__(256) void gmax_all(GmaxArgs A, unsigned* __restrict__ gi) {
    int ty = blockIdx.y;
    int n = A.n[ty];
    int r0 = blockIdx.x * 64;
    if (r0 >= n) return;
    int col = threadIdx.x;
    const float* hp = A.hp[ty];
    const int* grp = A.grp[ty];
    int cbase = A.colBase[ty];
    int rend = (r0 + 64 < n) ? r0 + 64 : n;
    int cur = grp[r0];
    float m = -INFINITY;
    for (int r = r0; r < rend; ++r) {
        int g = grp[r];
        if (g != cur) {
            atomicMax(&gi[cur * 768 + cbase + col], encf(m));
            cur = g; m = -INFINITY;
        }
        m = fmaxf(m, hp[(size_t)r * 256 + col]);
    }
    atomicMax(&gi[cur * 768 + cbase + col], encf(m));
}

__global__ void gi_init(unsigned* __restrict__ gi) {
    int i = blockIdx.x * 256 + threadIdx.x;
    if (i < 16 * 768) gi[i] = 0x007FFFFFu;
}

// ---------- final ----------
__global__ __launch_bounds__(1024) void final_k(const unsigned* __restrict__ gi,
                                                const float* __restrict__ out_w,
                                                const float* __restrict__ out_b,
                                                const float* __restrict__ y,
                                                float* __restrict__ out) {
    int w = threadIdx.x >> 6, lane = threadIdx.x & 63;
    float s = 0.f;
    for (int c = lane; c < 768; c += 64) s += decf(gi[w * 768 + c]) * out_w[c];
    #pragma unroll
    for (int d = 1; d < 64; d <<= 1) s += __shfl_xor(s, d);
    __shared__ float lloss[16];
    if (lane == 0) {
        float z = s + out_b[0];
        out[1 + w] = 1.f / (1.f + expf(-z));
        lloss[w] = fmaxf(z, 0.f) - z * y[w] + log1pf(expf(-fabsf(z)));
    }
    __syncthreads();
    if (threadIdx.x == 0) {
        float L = 0.f;
        for (int g2 = 0; g2 < 16; ++g2) L += lloss[g2];
        out[0] = L * (1.f / 16.f);
    }
}

extern "C" void kernel_launch(void* const* d_in, const int* in_sizes, int n_in,
                              void* d_out, int out_size, void* d_ws, size_t ws_size,
                              hipStream_t stream) {
    const int* word_id   = (const int*)d_in[0];
    const int* topic_id  = (const int*)d_in[1];
    const int* g_word    = (const int*)d_in[2];
    const int* g_topic   = (const int*)d_in[3];
    const int* g_doc     = (const int*)d_in[4];
    const int* src_ww = (const int*)d_in[5];  const int* dst_ww = (const int*)d_in[6];  const int* time_ww = (const int*)d_in[7];
    const int* src_wd = (const int*)d_in[8];  const int* dst_wd = (const int*)d_in[9];  const int* time_wd = (const int*)d_in[10];
    const int* src_wt = (const int*)d_in[11]; const int* dst_wt = (const int*)d_in[12]; const int* time_wt = (const int*)d_in[13];
    const int* src_td = (const int*)d_in[14]; const int* dst_td = (const int*)d_in[15]; const int* time_td = (const int*)d_in[16];
    const int* src_tt = (const int*)d_in[17]; const int* dst_tt = (const int*)d_in[18];
    const float* y_data      = (const float*)d_in[19];
    const float* word_embeds = (const float*)d_in[20];
    const float* topic_embeds= (const float*)d_in[21];
    const float* doc_gen     = (const float*)d_in[22];
    const float* adapt_w     = (const float*)d_in[23];
    const float* adapt_b     = (const float*)d_in[24];
    const float* time_tab    = (const float*)d_in[25];
    const float* time_w      = (const float*)d_in[26];
    const float* time_b      = (const float*)d_in[27];
    const float* kW = (const float*)d_in[28];
    const float* qW = (const float*)d_in[29];
    const float* vW = (const float*)d_in[30];
    const float* aW = (const float*)d_in[31];
    const float* kB = (const float*)d_in[32];
    const float* qB = (const float*)d_in[33];
    const float* vB = (const float*)d_in[34];
    const float* aB = (const float*)d_in[35];
    const float* skip = (const float*)d_in[36];
    const float* ln_g = (const float*)d_in[37];
    const float* ln_b = (const float*)d_in[38];
    const float* pri  = (const float*)d_in[39];
    const float* attR = (const float*)d_in[40];
    const float* msgR = (const float*)d_in[41];
    const float* out_w = (const float*)d_in[42];
    const float* out_b = (const float*)d_in[43];

    const int NW = in_sizes[0], NT = in_sizes[1], ND = in_sizes[4];
    const int E_ww = in_sizes[5], E_wd = in_sizes[8], E_wt = in_sizes[11],
              E_td = in_sizes[14], E_tt = in_sizes[17];
    const int nN[3] = {NW, NT, ND};
    const float invNin[3] = {1.f / 3.f, 1.f / 3.f, 1.f / 2.f};

    struct Rel { int e, s, d; const int* src; const int* dst; const int* tim; int E; };
    const Rel rels[8] = {
        {0, 0, 1, src_wt, dst_wt, time_wt, E_wt},
        {1, 0, 2, src_wd, dst_wd, time_wd, E_wd},
        {2, 1, 2, src_td, dst_td, time_td, E_td},
        {3, 1, 1, src_tt, dst_tt, nullptr, E_tt},
        {4, 0, 0, src_ww, dst_ww, time_ww, E_ww},
        {5, 1, 0, dst_wt, src_wt, time_wt, E_wt},
        {6, 2, 1, dst_td, src_td, time_td, E_td},
        {7, 2, 0, dst_wd, src_wd, time_wd, E_wd},
    };

    int relOfs[9]; relOfs[0] = 0;
    int dstBase[8]; int acc = 0;
    for (int r = 0; r < 8; ++r) { relOfs[r + 1] = relOfs[r] + rels[r].E; dstBase[r] = acc; acc += nN[rels[r].d]; }
    const int totE = relOfs[8], totD = acc;

    // per-rel rows in the shared katt/vmsg arena
    int relRowOfs[8], relRowsTot = 0, maxRelRows = 0;
    for (int r = 0; r < 8; ++r) {
        relRowOfs[r] = relRowsTot;
        relRowsTot += nN[rels[r].s];
        if (nN[rels[r].s] > maxRelRows) maxRelRows = nN[rels[r].s];
    }

    int nPad[3], rowOfsT[4];
    rowOfsT[0] = 0;
    for (int i = 0; i < 3; ++i) { nPad[i] = (nN[i] + 63) & ~63; rowOfsT[i + 1] = rowOfsT[i] + nPad[i]; }
    const int totPad = rowOfsT[3];

    float* base = (float*)d_ws;
    size_t off = 0;
    auto take = [&](size_t nElems) { float* p = base + off; off += (nElems + 63) & ~(size_t)63; return p; };
    float* hPbase = take((size_t)totPad * 256);
    unsigned short* hB = (unsigned short*)take((size_t)totPad * 128);
    unsigned short* tB = (unsigned short*)take((size_t)totPad * 128);
    unsigned short* kPb = (unsigned short*)take((size_t)totPad * 128);
    unsigned short* qPb = (unsigned short*)take((size_t)totPad * 128);
    unsigned short* vPb = (unsigned short*)take((size_t)totPad * 128);
    size_t arenaFloats = (size_t)relRowsTot * 128;
    if ((size_t)totPad * 256 > arenaFloats) arenaFloats = (size_t)totPad * 256;
    float* uni = take(arenaFloats);
    unsigned short* arena = (unsigned short*)uni;
    float* trans = uni;
    unsigned short* WT = (unsigned short*)take((size_t)25 * 32768);
    float* alogC = take((size_t)totE * 8);
    float* te7  = take(7 * 32);
    unsigned* gi = (unsigned*)take(16 * 768);
    int* cntAll = (int*)take(totD);
    int* part   = (int*)take(totD);
    int* bsum   = (int*)take(256);
    int* rowptrAll = (int*)take(totD + 1);
    int* curAll = (int*)take(totD);
    int* payload = (int*)take(totE);
    int* drel    = (int*)take(totE);
    (void)ws_size; (void)n_in; (void)out_size;

    te_kernel<<<1, 256, 0, stream>>>(time_tab, time_w, time_b, te7);
    {
        dim3 g(8, 8, 25);
        wtr_kernel<<<g, 256, 0, stream>>>(adapt_w, kW, qW, vW, aW, WT);
    }
    CsrArgs ca;
    for (int r = 0; r < 8; ++r) {
        ca.dst[r] = rels[r].dst; ca.srcA[r] = rels[r].src; ca.timA[r] = rels[r].tim;
        ca.dstBase[r] = dstBase[r];
    }
    for (int r = 0; r < 9; ++r) ca.relOfs[r] = relOfs[r];
    hipMemsetAsync(cntAll, 0, (size_t)totD * sizeof(int), stream);
    count_all<<<(totE + 255) / 256, 256, 0, stream>>>(ca, cntAll, totE);
    int nb = (totD + 1023) / 1024;
    scan1_k<<<nb, 1024, 0, stream>>>(cntAll, part, bsum, totD);
    scan2_k<<<1, 256, 0, stream>>>(bsum, nb);
    scan3_k<<<(totD + 255) / 256, 256, 0, stream>>>(cntAll, part, bsum, rowptrAll, curAll, totD);
    scatter_all<<<(totE + 255) / 256, 256, 0, stream>>>(ca, curAll, payload, drel, totE);
    gi_init<<<48, 256, 0, stream>>>(gi);

    {
        dim3 g((NW + 63) / 64, 4);
        gemm_init<<<g, 256, 0, stream>>>(word_embeds, word_id, WT, adapt_b, hPbase, hB, NW);
    }
    gather_rows<<<NT, 256, 0, stream>>>(topic_embeds, topic_id,
                                        hPbase + (size_t)rowOfsT[1] * 256,
                                        hB + (size_t)rowOfsT[1] * 256, NT);
    bcast_row<<<ND, 256, 0, stream>>>(doc_gen,
                                      hPbase + (size_t)rowOfsT[2] * 256,
                                      hB + (size_t)rowOfsT[2] * 256, ND);

    // ---- flattened arg structs ----
    BdAllArgs ba;
    Ek1PosArgs e1;
    Ek3AllArgs e3;
    for (int r = 0; r < 8; ++r) {
        const Rel& R = rels[r];
        ba.rows[r] = nN[R.s];
        ba.srcOfs[r] = rowOfsT[R.s];
        ba.outOfs[r] = relRowOfs[r];
        e1.kOfs[r] = relRowOfs[r]; e1.qOfs[r] = rowOfsT[R.d];
        e3.dstBase[r] = dstBase[r]; e3.vOfs[r] = relRowOfs[r];
        e3.hasTim[r] = (R.tim != nullptr) ? 1 : 0;
    }
    const int typeRel[9] = {4, 5, 7, 0, 3, 6, 1, 2, 0};
    for (int i = 0; i < 9; ++i) e3.typeRel[i] = typeRel[i];
    e3.nrT[0] = 3; e3.nrT[1] = 3; e3.nrT[2] = 2;
    e3.cumN[0] = 0; e3.cumN[1] = NW; e3.cumN[2] = NW + NT; e3.cumN[3] = NW + NT + ND;
    for (int i = 0; i < 3; ++i) { e3.tOfs[i] = rowOfsT[i]; e3.oScale[i] = invNin[i]; }

    GBArgs gb;
    for (int i = 0; i < 4; ++i) gb.rb[i] = rowOfsT[i] / 64;
    for (int i = 0; i < 3; ++i) gb.nLoc[i] = nN[i];
    MLArgs ml;
    for (int i = 0; i < 4; ++i) ml.rowOfs[i] = rowOfsT[i];
    for (int i = 0; i < 3; ++i) ml.nLoc[i] = nN[i];

    const int totBlocks = totPad / 64;
    const int totD3 = NW + NT + ND;
    for (int li = 0; li < LNUM; ++li) {
        gb.li3 = li * 3; ml.li3 = li * 3;
        {
            dim3 g(totBlocks, 4);
            gemm_batch<<<g, 256, 0, stream>>>(hB, WT, 1, 3, kB, qB, vB,
                                              kPb, qPb, vPb, 1, gb);
        }
        {
            dim3 g((maxRelRows + 127) / 128, 8, 8);
            bd_all<<<g, 256, 0, stream>>>(kPb, attR + (size_t)li * 8 * 8192,
                                          pri + (size_t)li * 8 * 8, 0, arena, ba);
        }
        ek1_pos<<<((size_t)totE * 8 + 255) / 256, 256, 0, stream>>>(
            qPb, arena, payload, drel, alogC, e1, totE);
        {
            dim3 g((maxRelRows + 127) / 128, 8, 8);
            bd_all<<<g, 256, 0, stream>>>(vPb, msgR + (size_t)li * 8 * 8192,
                                          pri + (size_t)li * 8 * 8, 1, arena, ba);
        }
        ek3_all<<<(totD3 + 3) / 4, 256, 0, stream>>>(arena, alogC, rowptrAll, payload,
                                                     te7, tB, e3);
        {
            dim3 g(totBlocks, 4);
            gemm_batch<<<g, 256, 0, stream>>>(tB, WT, 19, 1, aB, aB, aB,
                                              trans, trans, trans, 0, gb);
        }
        mix_ln_all<<<totPad, 256, 0, stream>>>(hPbase, hB, trans, skip, ln_g, ln_b, ml);
    }

    GmaxArgs ga;
    ga.hp[0] = hPbase + (size_t)rowOfsT[2] * 256; ga.grp[0] = g_doc;   ga.n[0] = ND; ga.colBase[0] = 0;
    ga.hp[1] = hPbase;                             ga.grp[1] = g_word;  ga.n[1] = NW; ga.colBase[1] = 256;
    ga.hp[2] = hPbase + (size_t)rowOfsT[1] * 256; ga.grp[2] = g_topic; ga.n[2] = NT; ga.colBase[2] = 512;
    int maxN = NW > ND ? (NW > NT ? NW : NT) : (ND > NT ? ND : NT);
    dim3 gg((maxN + 63) / 64, 3);
    gmax_all<<<gg, 256, 0, stream>>>(ga, gi);
    final_k<<<1, 1024, 0, stream>>>(gi, out_w, out_b, y_data, (float*)d_out);
}